// Round 15
// baseline (4120.330 us; speedup 1.0000x reference)
//
#include <hip/hip_runtime.h>
#include <stdint.h>

#define NB 256      // batch
#define TSEQ 1024   // sequence length
#define TT_MAX 64

// W_hh per-row split (128 f16-pairs per gate row): 28 reg + 48 LDS + 52 stream
#define REG_P 28
#define LDS_P 48
#define STR_P 52
#define LDSTR 148   // u32 stride of per-thread LDS slice (0 conflicts measured R13/R14)

typedef _Float16 f16;
typedef _Float16 h2 __attribute__((ext_vector_type(2)));

static __device__ __forceinline__ uint32_t pkh2(float a, float b) {
  h2 v; v[0] = (f16)a; v[1] = (f16)b;
  return __builtin_bit_cast(uint32_t, v);
}

#if __has_builtin(__builtin_amdgcn_fdot2)
static __device__ __forceinline__ float dot2u(uint32_t w, uint32_t h, float c) {
  return __builtin_amdgcn_fdot2(__builtin_bit_cast(h2, w), __builtin_bit_cast(h2, h), c, false);
}
#else
static __device__ __forceinline__ float dot2u(uint32_t w, uint32_t h, float c) {
  h2 a = __builtin_bit_cast(h2, w), b = __builtin_bit_cast(h2, h);
  return c + (float)a[0] * (float)b[0] + (float)a[1] * (float)b[1];
}
#endif

#if __has_builtin(__builtin_amdgcn_rcpf)
#define RCPF(x) __builtin_amdgcn_rcpf(x)
#else
#define RCPF(x) (1.0f / (x))
#endif

static __device__ __forceinline__ float sigm(float x) {
  return RCPF(1.0f + exp2f(-1.44269504f * x));
}
static __device__ __forceinline__ float tanh_f(float x) {
  return 1.0f - 2.0f * RCPF(1.0f + exp2f(2.88539008f * x));
}

// LDS-visibility barrier WITHOUT the vmcnt(0) drain of __syncthreads().
// Safe here: all cross-lane communication (encp/zu/hf) is via LDS; global
// loads (weight stream, activation prefetch) are private to the issuing
// thread. Keeps the software-pipelined vmem loads in flight across barriers.
static __device__ __forceinline__ void bar_lds() {
  asm volatile("s_waitcnt lgkmcnt(0)\n\ts_barrier" ::: "memory");
}

// ---------------------------------------------------------------------------
// One-time weight pack (f16). Thread t owns gate rows (t, t+256, t+512).
//  whr : reg part,    [(rr*7  + p/4)*256 + t] uint4, pairs [0,28)
//  whl : LDS part,    [t*LDSTR + rr*48 + p],         pairs [28,76)
//  whs : stream part, [(rr*13 + p/4)*256 + t] uint4, pairs [76,128)
//  whz : W_ih z-cols, [(rr*4  + p/4)*256 + t] uint4, 16 pairs
//  wep : enc h-part,  [(p/4)*256 + t] uint4 — thread t holds enc row e=t&63,
//        k-pairs pc = (t>>6)*32 + p
// ---------------------------------------------------------------------------
__global__ __launch_bounds__(256) void vrnn_pack(
    const float* __restrict__ W_hh, const float* __restrict__ W_ih,
    const float* __restrict__ emW, const float* __restrict__ esW,
    uint32_t* __restrict__ whr, uint32_t* __restrict__ whl,
    uint32_t* __restrict__ whs, uint32_t* __restrict__ whz,
    uint32_t* __restrict__ wep)
{
  const int t = threadIdx.x;
  for (int rr = 0; rr < 3; ++rr) {
    const float* R = W_hh + (size_t)(t + rr * 256) * 256;
    for (int p = 0; p < REG_P; ++p)
      whr[(((size_t)rr * 7 + (p >> 2)) * 256 + t) * 4 + (p & 3)] = pkh2(R[2 * p], R[2 * p + 1]);
    for (int p = 0; p < LDS_P; ++p)
      whl[(size_t)t * LDSTR + rr * LDS_P + p] = pkh2(R[2 * (p + REG_P)], R[2 * (p + REG_P) + 1]);
    for (int p = 0; p < STR_P; ++p)
      whs[(((size_t)rr * 13 + (p >> 2)) * 256 + t) * 4 + (p & 3)] =
          pkh2(R[2 * (p + REG_P + LDS_P)], R[2 * (p + REG_P + LDS_P) + 1]);
    const float* Z = W_ih + (size_t)(t + rr * 256) * 96 + 64;
    for (int p = 0; p < 16; ++p)
      whz[(((size_t)rr * 4 + (p >> 2)) * 256 + t) * 4 + (p & 3)] = pkh2(Z[2 * p], Z[2 * p + 1]);
  }
  const int e = t & 63, s = t >> 6;
  const float* src = (e < 32) ? (emW + (size_t)e * 320 + 64)
                              : (esW + (size_t)(e - 32) * 320 + 64);
  for (int p = 0; p < 32; ++p) {
    int pc = s * 32 + p;
    wep[(((size_t)(p >> 2)) * 256 + t) * 4 + (p & 3)] = pkh2(src[2 * pc], src[2 * pc + 1]);
  }
}

// ---------------------------------------------------------------------------
// Precompute kernel (unchanged): gi_x'[t][b][768], zx'[t][b][64]
// ---------------------------------------------------------------------------
__global__ __launch_bounds__(256, 2) void vrnn_pre(
    const float* __restrict__ x, const float* __restrict__ W_ih,
    const float* __restrict__ b_ih, const float* __restrict__ b_hh,
    const float* __restrict__ emW, const float* __restrict__ emb,
    const float* __restrict__ esW, const float* __restrict__ esb,
    f16* __restrict__ gix, f16* __restrict__ zx,
    int chunk_t0, int TT, int nTT)
{
  const int tid = threadIdx.x;
  const int b  = blockIdx.x / nTT;
  const int tt = blockIdx.x % nTT;
  const int tloc0 = tt * TT;

  uint32_t wx[3][32];
  float bias[3];
  #pragma unroll
  for (int rr = 0; rr < 3; ++rr) {
    int j = tid + rr * 256;
    const float4* wr = (const float4*)(W_ih + (size_t)j * 96);
    #pragma unroll
    for (int p4 = 0; p4 < 16; ++p4) {
      float4 v = wr[p4];
      wx[rr][2 * p4]     = pkh2(v.x, v.y);
      wx[rr][2 * p4 + 1] = pkh2(v.z, v.w);
    }
    bias[rr] = b_ih[j] + (rr < 2 ? b_hh[j] : 0.0f);  // fold b_hh into r,z rows only
  }
  uint32_t we[32]; float ebias = 0.0f;
  if (tid < 64) {
    const float* src = (tid < 32) ? (emW + (size_t)tid * 320)
                                  : (esW + (size_t)(tid - 32) * 320);
    #pragma unroll
    for (int p = 0; p < 32; ++p) we[p] = pkh2(src[2 * p], src[2 * p + 1]);
    ebias = (tid < 32) ? emb[tid] : esb[tid - 32];
  }

  __shared__ uint32_t xs[TT_MAX * 32];
  for (int idx = tid; idx < TT * 32; idx += 256) {
    int tl = idx >> 5, pk = idx & 31;
    size_t base = ((size_t)b * TSEQ + (chunk_t0 + tloc0 + tl)) * 64 + 2 * pk;
    xs[idx] = pkh2(x[base], x[base + 1]);
  }
  __syncthreads();

  for (int tl = 0; tl < TT; ++tl) {
    float a0 = bias[0], a1 = bias[1], a2 = bias[2];
    #pragma unroll
    for (int p = 0; p < 32; ++p) {
      uint32_t u = xs[tl * 32 + p];
      a0 = dot2u(wx[0][p], u, a0);
      a1 = dot2u(wx[1][p], u, a1);
      a2 = dot2u(wx[2][p], u, a2);
    }
    size_t ob = (size_t)(tloc0 + tl) * NB + b;
    f16* g = gix + ob * 768;
    g[tid] = (f16)a0; g[tid + 256] = (f16)a1; g[tid + 512] = (f16)a2;
    if (tid < 64) {
      float a3 = ebias;
      #pragma unroll
      for (int p = 0; p < 32; ++p) a3 = dot2u(we[p], xs[tl * 32 + p], a3);
      zx[ob * 64 + tid] = (f16)a3;
    }
  }
}

// ---------------------------------------------------------------------------
// Recurrent kernel v8: R14 structure + vmcnt-preserving barriers.
// R14 post-mortem: __syncthreads() drains vmcnt(0) at each of 3 barriers/step,
// killing the stream pipeline at every barrier (VALUBusy stuck at 48%).
// bar_lds() waits lgkmcnt(0) only — LDS communication stays correct, global
// prefetches stay in flight. Also: 2 accumulators in the serial fdot2 chains
// (stream consume: 52-long; phase A: 32-long) to halve dependency stalls.
// ---------------------------------------------------------------------------
__global__ __launch_bounds__(256, 2) void vrnn_rec(
    const f16* __restrict__ gix, const f16* __restrict__ zx,
    const float* __restrict__ eps,
    const uint32_t* __restrict__ whr, const uint32_t* __restrict__ whl_g,
    const uint32_t* __restrict__ whs, const uint32_t* __restrict__ whz,
    const uint32_t* __restrict__ wep_g,
    const float* __restrict__ b_hh,
    float* __restrict__ hws, float* __restrict__ out,
    int t0, int Tlen, int first, int last)
{
  const int t = threadIdx.x;
  const int b = blockIdx.x;

  // ---- pinned register weights ----
  uint32_t wrg[3][REG_P];              // 84
  {
    const uint4* w4 = (const uint4*)whr;
    #pragma unroll
    for (int c = 0; c < 21; ++c) {
      uint4 v = w4[c * 256 + t];
      int rr = c / 7, p4 = c % 7;
      wrg[rr][4 * p4] = v.x; wrg[rr][4 * p4 + 1] = v.y;
      wrg[rr][4 * p4 + 2] = v.z; wrg[rr][4 * p4 + 3] = v.w;
    }
  }
  uint32_t wz[3][16];                  // 48
  {
    const uint4* w4 = (const uint4*)whz;
    #pragma unroll
    for (int c = 0; c < 12; ++c) {
      uint4 v = w4[c * 256 + t];
      int rr = c / 4, p4 = c % 4;
      wz[rr][4 * p4] = v.x; wz[rr][4 * p4 + 1] = v.y;
      wz[rr][4 * p4 + 2] = v.z; wz[rr][4 * p4 + 3] = v.w;
    }
  }
  uint32_t we[32];                     // 32
  {
    const uint4* w4 = (const uint4*)wep_g;
    #pragma unroll
    for (int c = 0; c < 8; ++c) {
      uint4 v = w4[c * 256 + t];
      we[4 * c] = v.x; we[4 * c + 1] = v.y; we[4 * c + 2] = v.z; we[4 * c + 3] = v.w;
    }
  }
  #pragma unroll
  for (int rr = 0; rr < 3; ++rr) {
    #pragma unroll
    for (int i = 0; i < REG_P; ++i) asm volatile("" : "+v"(wrg[rr][i]));
    #pragma unroll
    for (int i = 0; i < 16; ++i)   asm volatile("" : "+v"(wz[rr][i]));
  }
  #pragma unroll
  for (int i = 0; i < 32; ++i) asm volatile("" : "+v"(we[i]));
  const float bhn = b_hh[512 + t];

  // ---- LDS (~154 KB) ----
  __shared__ uint32_t lwh[256 * LDSTR];          // 151,552 B
  __shared__ __align__(16) f16 hf[2][256];
  __shared__ float encp[256];
  __shared__ uint32_t zu[16];

  {
    const uint4* src = (const uint4*)(whl_g + (size_t)t * LDSTR);
    uint4* dst = (uint4*)(lwh + (size_t)t * LDSTR);
    #pragma unroll
    for (int j = 0; j < LDSTR / 4; ++j) dst[j] = src[j];
  }

  float hm = first ? 0.0f : hws[b * 256 + t];
  hf[0][t] = (f16)hm;
  __syncthreads();   // once, outside the loop — full drain is fine here

  // ---- stream prefetch for t=0 ----
  const f16* gp0 = gix + (size_t)b * 768;
  float pf_g0 = (float)gp0[t], pf_g1 = (float)gp0[t + 256], pf_g2 = (float)gp0[t + 512];
  float pf_zm = 0.0f, pf_zl = 0.0f, pf_ep = 0.0f;
  if (t < 32) {
    const f16* zp = zx + (size_t)b * 64;
    pf_zm = (float)zp[t]; pf_zl = (float)zp[32 + t];
    pf_ep = eps[((size_t)t0 * NB + b) * 32 + t];
  }

  const int s = t >> 6;                      // wave id (phase-A k-slice)
  const uint32_t* myl = lwh + (size_t)t * LDSTR;
  const uint4* whs4 = (const uint4*)whs;

  // ---- preload stream chunk rr=0 for step 0 ----
  uint4 sbuf[13];
  #pragma unroll
  for (int j = 0; j < 13; ++j) sbuf[j] = whs4[j * 256 + t];
  __builtin_amdgcn_sched_barrier(0);

  for (int tl = 0; tl < Tlen; ++tl) {
    const int cur = tl & 1, nxt = cur ^ 1;
    const uint32_t* hu = (const uint32_t*)&hf[cur][0];
    const uint4* hu4 = (const uint4*)hu;

    // ---- phase A: encoder partials (2 accumulators, wave-uniform h bcast) ----
    float epa = 0.0f, epb = 0.0f;
    #pragma unroll
    for (int p = 0; p < 32; p += 2) {
      epa = dot2u(we[p],     hu[s * 32 + p],     epa);
      epb = dot2u(we[p + 1], hu[s * 32 + p + 1], epb);
    }
    encp[t] = epa + epb;
    bar_lds();  // b1

    // ---- phase B: z (32 threads) || gh (all threads) ----
    if (t < 32) {
      float mu = pf_zm, lv = pf_zl;
      #pragma unroll
      for (int ss = 0; ss < 4; ++ss) {
        mu += encp[ss * 64 + t];
        lv += encp[ss * 64 + 32 + t];
      }
      float z = mu + pf_ep * exp2f(0.72134752f * lv);   // mu + eps*exp(0.5*lv)
      ((f16*)zu)[t] = (f16)z;
    }
    float g0 = 0.0f, g1 = 0.0f, g2 = 0.0f;
    // pairs [0,28): register weights
    #pragma unroll
    for (int g4 = 0; g4 < 7; ++g4) {
      uint4 u4 = hu4[g4];
      g0 = dot2u(wrg[0][4 * g4],     u4.x, g0);
      g1 = dot2u(wrg[1][4 * g4],     u4.x, g1);
      g2 = dot2u(wrg[2][4 * g4],     u4.x, g2);
      g0 = dot2u(wrg[0][4 * g4 + 1], u4.y, g0);
      g1 = dot2u(wrg[1][4 * g4 + 1], u4.y, g1);
      g2 = dot2u(wrg[2][4 * g4 + 1], u4.y, g2);
      g0 = dot2u(wrg[0][4 * g4 + 2], u4.z, g0);
      g1 = dot2u(wrg[1][4 * g4 + 2], u4.z, g1);
      g2 = dot2u(wrg[2][4 * g4 + 2], u4.z, g2);
      g0 = dot2u(wrg[0][4 * g4 + 3], u4.w, g0);
      g1 = dot2u(wrg[1][4 * g4 + 3], u4.w, g1);
      g2 = dot2u(wrg[2][4 * g4 + 3], u4.w, g2);
    }
    // consume stream rr0 (2 accumulators) -> g0; issue rr1
    {
      float a = 0.0f, a2 = 0.0f;
      #pragma unroll
      for (int j = 0; j < 13; ++j) {
        uint4 u4 = hu4[19 + j];
        a  = dot2u(sbuf[j].x, u4.x, a);
        a2 = dot2u(sbuf[j].y, u4.y, a2);
        a  = dot2u(sbuf[j].z, u4.z, a);
        a2 = dot2u(sbuf[j].w, u4.w, a2);
      }
      g0 += a + a2;
    }
    #pragma unroll
    for (int j = 0; j < 13; ++j) sbuf[j] = whs4[(13 + j) * 256 + t];
    __builtin_amdgcn_sched_barrier(0);
    // pairs [28,76) first half: LDS groups 0..5
    #pragma unroll
    for (int g4 = 0; g4 < 6; ++g4) {
      uint4 u4 = hu4[7 + g4];
      uint4 w0 = *(const uint4*)(myl + 0 * LDS_P + 4 * g4);
      uint4 w1 = *(const uint4*)(myl + 1 * LDS_P + 4 * g4);
      uint4 w2 = *(const uint4*)(myl + 2 * LDS_P + 4 * g4);
      g0 = dot2u(w0.x, u4.x, g0); g1 = dot2u(w1.x, u4.x, g1); g2 = dot2u(w2.x, u4.x, g2);
      g0 = dot2u(w0.y, u4.y, g0); g1 = dot2u(w1.y, u4.y, g1); g2 = dot2u(w2.y, u4.y, g2);
      g0 = dot2u(w0.z, u4.z, g0); g1 = dot2u(w1.z, u4.z, g1); g2 = dot2u(w2.z, u4.z, g2);
      g0 = dot2u(w0.w, u4.w, g0); g1 = dot2u(w1.w, u4.w, g1); g2 = dot2u(w2.w, u4.w, g2);
    }
    // consume stream rr1 -> g1; issue rr2
    {
      float a = 0.0f, a2 = 0.0f;
      #pragma unroll
      for (int j = 0; j < 13; ++j) {
        uint4 u4 = hu4[19 + j];
        a  = dot2u(sbuf[j].x, u4.x, a);
        a2 = dot2u(sbuf[j].y, u4.y, a2);
        a  = dot2u(sbuf[j].z, u4.z, a);
        a2 = dot2u(sbuf[j].w, u4.w, a2);
      }
      g1 += a + a2;
    }
    #pragma unroll
    for (int j = 0; j < 13; ++j) sbuf[j] = whs4[(26 + j) * 256 + t];
    __builtin_amdgcn_sched_barrier(0);
    // pairs [28,76) second half: LDS groups 6..11
    #pragma unroll
    for (int g4 = 6; g4 < 12; ++g4) {
      uint4 u4 = hu4[7 + g4];
      uint4 w0 = *(const uint4*)(myl + 0 * LDS_P + 4 * g4);
      uint4 w1 = *(const uint4*)(myl + 1 * LDS_P + 4 * g4);
      uint4 w2 = *(const uint4*)(myl + 2 * LDS_P + 4 * g4);
      g0 = dot2u(w0.x, u4.x, g0); g1 = dot2u(w1.x, u4.x, g1); g2 = dot2u(w2.x, u4.x, g2);
      g0 = dot2u(w0.y, u4.y, g0); g1 = dot2u(w1.y, u4.y, g1); g2 = dot2u(w2.y, u4.y, g2);
      g0 = dot2u(w0.z, u4.z, g0); g1 = dot2u(w1.z, u4.z, g1); g2 = dot2u(w2.z, u4.z, g2);
      g0 = dot2u(w0.w, u4.w, g0); g1 = dot2u(w1.w, u4.w, g1); g2 = dot2u(w2.w, u4.w, g2);
    }
    // consume stream rr2 -> g2
    {
      float a = 0.0f, a2 = 0.0f;
      #pragma unroll
      for (int j = 0; j < 13; ++j) {
        uint4 u4 = hu4[19 + j];
        a  = dot2u(sbuf[j].x, u4.x, a);
        a2 = dot2u(sbuf[j].y, u4.y, a2);
        a  = dot2u(sbuf[j].z, u4.z, a);
        a2 = dot2u(sbuf[j].w, u4.w, a2);
      }
      g2 += a + a2;
    }
    bar_lds();  // b2  (zu visible)

    // ---- phase C: gi_z from broadcast z, gates ----
    float q0 = 0.0f, q1 = 0.0f, q2 = 0.0f;
    #pragma unroll
    for (int p = 0; p < 16; ++p) {
      uint32_t u = zu[p];          // broadcast reads
      q0 = dot2u(wz[0][p], u, q0);
      q1 = dot2u(wz[1][p], u, q1);
      q2 = dot2u(wz[2][p], u, q2);
    }
    float r  = sigm(pf_g0 + g0 + q0);
    float uu = sigm(pf_g1 + g1 + q1);
    float n  = tanh_f(pf_g2 + q2 + r * (g2 + bhn));
    hm = (1.0f - uu) * n + uu * hm;
    hf[nxt][t] = (f16)hm;

    // ---- issue stream rr0 for NEXT step (stays in flight across bar_lds) ----
    #pragma unroll
    for (int j = 0; j < 13; ++j) sbuf[j] = whs4[j * 256 + t];
    __builtin_amdgcn_sched_barrier(0);

    // ---- prefetch activation streams for tl+1 ----
    int tn = (tl + 1 < Tlen) ? tl + 1 : tl;
    const f16* gp = gix + ((size_t)tn * NB + b) * 768;
    pf_g0 = (float)gp[t]; pf_g1 = (float)gp[t + 256]; pf_g2 = (float)gp[t + 512];
    if (t < 32) {
      const f16* zp = zx + ((size_t)tn * NB + b) * 64;
      pf_zm = (float)zp[t]; pf_zl = (float)zp[32 + t];
      pf_ep = eps[((size_t)(t0 + tn) * NB + b) * 32 + t];
    }
    bar_lds();  // b3  (h_new visible)
  }

  if (last) out[b * 256 + t] = hm;
  else      hws[b * 256 + t] = hm;
}

extern "C" void kernel_launch(void* const* d_in, const int* in_sizes, int n_in,
                              void* d_out, int out_size, void* d_ws, size_t ws_size,
                              hipStream_t stream) {
  const float* x    = (const float*)d_in[0];
  const float* eps  = (const float*)d_in[1];
  const float* emW  = (const float*)d_in[2];
  const float* emb  = (const float*)d_in[3];
  const float* esW  = (const float*)d_in[4];
  const float* esb  = (const float*)d_in[5];
  const float* W_ih = (const float*)d_in[10];
  const float* W_hh = (const float*)d_in[11];
  const float* b_ih = (const float*)d_in[12];
  const float* b_hh = (const float*)d_in[13];
  float* out = (float*)d_out;

  // workspace layout (16B-aligned regions)
  const size_t o_whr = 262144;                  // hws: 256 KB
  const size_t o_whl = o_whr + 86016;           // whr: 21*256*16
  const size_t o_whs = o_whl + 151552;          // whl: 148*256*4
  const size_t o_whz = o_whs + 159744;          // whs: 39*256*16
  const size_t o_wep = o_whz + 49152;           // whz: 12*256*16
  const size_t o_gix = o_wep + 32768;           // wep: 8*256*16  -> 741,376
  int Tc = TSEQ;
  while (Tc > 8 && o_gix + (size_t)Tc * NB * (768 + 64) * 2 > ws_size) Tc >>= 1;

  float*    hws   = (float*)d_ws;
  uint32_t* whr   = (uint32_t*)((char*)d_ws + o_whr);
  uint32_t* whl_g = (uint32_t*)((char*)d_ws + o_whl);
  uint32_t* whs   = (uint32_t*)((char*)d_ws + o_whs);
  uint32_t* whz   = (uint32_t*)((char*)d_ws + o_whz);
  uint32_t* wep   = (uint32_t*)((char*)d_ws + o_wep);
  f16*      gix   = (f16*)((char*)d_ws + o_gix);
  f16*      zx    = gix + (size_t)Tc * NB * 768;

  vrnn_pack<<<dim3(1), dim3(256), 0, stream>>>(W_hh, W_ih, emW, esW,
                                               whr, whl_g, whs, whz, wep);

  int nch = TSEQ / Tc;
  int TT  = Tc < 64 ? Tc : 64;
  int nTT = Tc / TT;

  for (int c = 0; c < nch; ++c) {
    vrnn_pre<<<dim3(NB * nTT), dim3(256), 0, stream>>>(
        x, W_ih, b_ih, b_hh, emW, emb, esW, esb, gix, zx, c * Tc, TT, nTT);
    vrnn_rec<<<dim3(NB), dim3(256), 0, stream>>>(
        gix, zx, eps, whr, whl_g, whs, whz, wep, b_hh, hws, out,
        c * Tc, Tc, c == 0 ? 1 : 0, c == nch - 1 ? 1 : 0);
  }
}

// Round 17
// 3271.728 us; speedup vs baseline: 1.2594x; 1.2594x over previous
//
#include <hip/hip_runtime.h>
#include <stdint.h>

#define NB 256      // batch
#define TSEQ 1024   // sequence length
#define TT_MAX 64

// W_hh per-row split (128 f16-pairs per gate row): 28 reg + 48 LDS + 52 stream
#define REG_P 28
#define LDS_P 48
#define STR_P 52
#define LDSTR 148   // u32 stride of per-thread LDS slice (0 conflicts measured R13/R14)

typedef _Float16 f16;
typedef _Float16 h2 __attribute__((ext_vector_type(2)));

static __device__ __forceinline__ uint32_t pkh2(float a, float b) {
  h2 v; v[0] = (f16)a; v[1] = (f16)b;
  return __builtin_bit_cast(uint32_t, v);
}

#if __has_builtin(__builtin_amdgcn_fdot2)
static __device__ __forceinline__ float dot2u(uint32_t w, uint32_t h, float c) {
  return __builtin_amdgcn_fdot2(__builtin_bit_cast(h2, w), __builtin_bit_cast(h2, h), c, false);
}
#else
static __device__ __forceinline__ float dot2u(uint32_t w, uint32_t h, float c) {
  h2 a = __builtin_bit_cast(h2, w), b = __builtin_bit_cast(h2, h);
  return c + (float)a[0] * (float)b[0] + (float)a[1] * (float)b[1];
}
#endif

#if __has_builtin(__builtin_amdgcn_rcpf)
#define RCPF(x) __builtin_amdgcn_rcpf(x)
#else
#define RCPF(x) (1.0f / (x))
#endif

static __device__ __forceinline__ float sigm(float x) {
  return RCPF(1.0f + exp2f(-1.44269504f * x));
}
static __device__ __forceinline__ float tanh_f(float x) {
  return 1.0f - 2.0f * RCPF(1.0f + exp2f(2.88539008f * x));
}

// ---------------------------------------------------------------------------
// One-time weight pack (f16). Thread t owns gate rows (t, t+256, t+512).
//  whr : reg part,    [(rr*7  + p/4)*256 + t] uint4, pairs [0,28)
//  whl : LDS part,    [t*LDSTR + rr*48 + p],         pairs [28,76)
//  whs : stream part, [(rr*13 + p/4)*256 + t] uint4, pairs [76,128)
//  whz : W_ih z-cols, [(rr*4  + p/4)*256 + t] uint4, 16 pairs
//  wep : enc h-part, WAVE-LOCAL z layout (R16): lane l=t&63 of wave w=t>>6,
//        rid=l>>2, kq=l&3. Enc row r = rid<8 ? 8w+rid : 32+8w+(rid-8)
//        (mu row e and lv row 32+e sit in lanes l and l+32 of ONE wave).
//        k-slice = kq*32 pairs, read-order ROTATED by (j+2kq)&7 (baked here)
//        so the 4 kq groups' b128 h-reads hit disjoint bank quads.
// ---------------------------------------------------------------------------
__global__ __launch_bounds__(256) void vrnn_pack(
    const float* __restrict__ W_hh, const float* __restrict__ W_ih,
    const float* __restrict__ emW, const float* __restrict__ esW,
    uint32_t* __restrict__ whr, uint32_t* __restrict__ whl,
    uint32_t* __restrict__ whs, uint32_t* __restrict__ whz,
    uint32_t* __restrict__ wep)
{
  const int t = threadIdx.x;
  for (int rr = 0; rr < 3; ++rr) {
    const float* R = W_hh + (size_t)(t + rr * 256) * 256;
    for (int p = 0; p < REG_P; ++p)
      whr[(((size_t)rr * 7 + (p >> 2)) * 256 + t) * 4 + (p & 3)] = pkh2(R[2 * p], R[2 * p + 1]);
    for (int p = 0; p < LDS_P; ++p)
      whl[(size_t)t * LDSTR + rr * LDS_P + p] = pkh2(R[2 * (p + REG_P)], R[2 * (p + REG_P) + 1]);
    for (int p = 0; p < STR_P; ++p)
      whs[(((size_t)rr * 13 + (p >> 2)) * 256 + t) * 4 + (p & 3)] =
          pkh2(R[2 * (p + REG_P + LDS_P)], R[2 * (p + REG_P + LDS_P) + 1]);
    const float* Z = W_ih + (size_t)(t + rr * 256) * 96 + 64;
    for (int p = 0; p < 16; ++p)
      whz[(((size_t)rr * 4 + (p >> 2)) * 256 + t) * 4 + (p & 3)] = pkh2(Z[2 * p], Z[2 * p + 1]);
  }
  {
    const int l = t & 63, w = t >> 6, rid = l >> 2, kq = l & 3;
    const int rot2 = (2 * kq) & 7;
    const int r = (rid < 8) ? (8 * w + rid) : (32 + 8 * w + (rid - 8));
    const float* esrc = (r < 32) ? (emW + (size_t)r * 320 + 64)
                                 : (esW + (size_t)(r - 32) * 320 + 64);
    for (int j = 0; j < 8; ++j)
      for (int c = 0; c < 4; ++c) {
        int pc = kq * 32 + ((j + rot2) & 7) * 4 + c;
        wep[((size_t)j * 256 + t) * 4 + c] = pkh2(esrc[2 * pc], esrc[2 * pc + 1]);
      }
  }
}

// ---------------------------------------------------------------------------
// Precompute kernel (unchanged): gi_x'[t][b][768], zx'[t][b][64]
// ---------------------------------------------------------------------------
__global__ __launch_bounds__(256, 2) void vrnn_pre(
    const float* __restrict__ x, const float* __restrict__ W_ih,
    const float* __restrict__ b_ih, const float* __restrict__ b_hh,
    const float* __restrict__ emW, const float* __restrict__ emb,
    const float* __restrict__ esW, const float* __restrict__ esb,
    f16* __restrict__ gix, f16* __restrict__ zx,
    int chunk_t0, int TT, int nTT)
{
  const int tid = threadIdx.x;
  const int b  = blockIdx.x / nTT;
  const int tt = blockIdx.x % nTT;
  const int tloc0 = tt * TT;

  uint32_t wx[3][32];
  float bias[3];
  #pragma unroll
  for (int rr = 0; rr < 3; ++rr) {
    int j = tid + rr * 256;
    const float4* wr = (const float4*)(W_ih + (size_t)j * 96);
    #pragma unroll
    for (int p4 = 0; p4 < 16; ++p4) {
      float4 v = wr[p4];
      wx[rr][2 * p4]     = pkh2(v.x, v.y);
      wx[rr][2 * p4 + 1] = pkh2(v.z, v.w);
    }
    bias[rr] = b_ih[j] + (rr < 2 ? b_hh[j] : 0.0f);  // fold b_hh into r,z rows only
  }
  uint32_t we[32]; float ebias = 0.0f;
  if (tid < 64) {
    const float* src = (tid < 32) ? (emW + (size_t)tid * 320)
                                  : (esW + (size_t)(tid - 32) * 320);
    #pragma unroll
    for (int p = 0; p < 32; ++p) we[p] = pkh2(src[2 * p], src[2 * p + 1]);
    ebias = (tid < 32) ? emb[tid] : esb[tid - 32];
  }

  __shared__ uint32_t xs[TT_MAX * 32];
  for (int idx = tid; idx < TT * 32; idx += 256) {
    int tl = idx >> 5, pk = idx & 31;
    size_t base = ((size_t)b * TSEQ + (chunk_t0 + tloc0 + tl)) * 64 + 2 * pk;
    xs[idx] = pkh2(x[base], x[base + 1]);
  }
  __syncthreads();

  for (int tl = 0; tl < TT; ++tl) {
    float a0 = bias[0], a1 = bias[1], a2 = bias[2];
    #pragma unroll
    for (int p = 0; p < 32; ++p) {
      uint32_t u = xs[tl * 32 + p];
      a0 = dot2u(wx[0][p], u, a0);
      a1 = dot2u(wx[1][p], u, a1);
      a2 = dot2u(wx[2][p], u, a2);
    }
    size_t ob = (size_t)(tloc0 + tl) * NB + b;
    f16* g = gix + ob * 768;
    g[tid] = (f16)a0; g[tid + 256] = (f16)a1; g[tid + 512] = (f16)a2;
    if (tid < 64) {
      float a3 = ebias;
      #pragma unroll
      for (int p = 0; p < 32; ++p) a3 = dot2u(we[p], xs[tl * 32 + p], a3);
      zx[ob * 64 + tid] = (f16)a3;
    }
  }
}

// ---------------------------------------------------------------------------
// Recurrent kernel v9: R14 structure (proven 1.35ms: __syncthreads barriers,
// single-acc chains, pipelined sbuf) with the z-path made WAVE-LOCAL:
// enc partials reduced by shfl_xor(1,2) butterfly, mu<->lv exchanged by
// shfl_xor(32) (rows e and 32+e live in lanes l and l+32 of one wave), z
// computed in-lane, zu written -- eliminates encp and barrier b1: now only
// 2 __syncthreads per step (zu-visible, h-visible).
// R15 lesson: inline-asm lgkmcnt-only barriers ("memory" clobber) made the
// scheduler conservative (VGPR 224->192, VALUBusy 48->31%) -- reverted.
// ---------------------------------------------------------------------------
__global__ __launch_bounds__(256, 2) void vrnn_rec(
    const f16* __restrict__ gix, const f16* __restrict__ zx,
    const float* __restrict__ eps,
    const uint32_t* __restrict__ whr, const uint32_t* __restrict__ whl_g,
    const uint32_t* __restrict__ whs, const uint32_t* __restrict__ whz,
    const uint32_t* __restrict__ wep_g,
    const float* __restrict__ b_hh,
    float* __restrict__ hws, float* __restrict__ out,
    int t0, int Tlen, int first, int last)
{
  const int t = threadIdx.x;
  const int b = blockIdx.x;

  // ---- pinned register weights ----
  uint32_t wrg[3][REG_P];              // 84
  {
    const uint4* w4 = (const uint4*)whr;
    #pragma unroll
    for (int c = 0; c < 21; ++c) {
      uint4 v = w4[c * 256 + t];
      int rr = c / 7, p4 = c % 7;
      wrg[rr][4 * p4] = v.x; wrg[rr][4 * p4 + 1] = v.y;
      wrg[rr][4 * p4 + 2] = v.z; wrg[rr][4 * p4 + 3] = v.w;
    }
  }
  uint32_t wz[3][16];                  // 48
  {
    const uint4* w4 = (const uint4*)whz;
    #pragma unroll
    for (int c = 0; c < 12; ++c) {
      uint4 v = w4[c * 256 + t];
      int rr = c / 4, p4 = c % 4;
      wz[rr][4 * p4] = v.x; wz[rr][4 * p4 + 1] = v.y;
      wz[rr][4 * p4 + 2] = v.z; wz[rr][4 * p4 + 3] = v.w;
    }
  }
  uint32_t we[32];                     // 32
  {
    const uint4* w4 = (const uint4*)wep_g;
    #pragma unroll
    for (int c = 0; c < 8; ++c) {
      uint4 v = w4[c * 256 + t];
      we[4 * c] = v.x; we[4 * c + 1] = v.y; we[4 * c + 2] = v.z; we[4 * c + 3] = v.w;
    }
  }
  #pragma unroll
  for (int rr = 0; rr < 3; ++rr) {
    #pragma unroll
    for (int i = 0; i < REG_P; ++i) asm volatile("" : "+v"(wrg[rr][i]));
    #pragma unroll
    for (int i = 0; i < 16; ++i)   asm volatile("" : "+v"(wz[rr][i]));
  }
  #pragma unroll
  for (int i = 0; i < 32; ++i) asm volatile("" : "+v"(we[i]));
  const float bhn = b_hh[512 + t];

  // ---- LDS (~153 KB) ----
  __shared__ uint32_t lwh[256 * LDSTR];          // 151,552 B
  __shared__ __align__(16) f16 hf[2][256];
  __shared__ uint32_t zu[16];

  {
    const uint4* src = (const uint4*)(whl_g + (size_t)t * LDSTR);
    uint4* dst = (uint4*)(lwh + (size_t)t * LDSTR);
    #pragma unroll
    for (int j = 0; j < LDSTR / 4; ++j) dst[j] = src[j];
  }

  float hm = first ? 0.0f : hws[b * 256 + t];
  hf[0][t] = (f16)hm;
  __syncthreads();   // once, outside the loop

  // ---- z-lane bookkeeping: lanes (t&35)==0 compute z for e = 8w + rid ----
  const int zlane = ((t & 35) == 0);
  const int ze    = 8 * (t >> 6) + ((t & 31) >> 2);
  const int base8 = (t & 3) * 8;
  const int rot2  = (2 * (t & 3)) & 7;

  // ---- stream prefetch for t=0 ----
  const f16* gp0 = gix + (size_t)b * 768;
  float pf_g0 = (float)gp0[t], pf_g1 = (float)gp0[t + 256], pf_g2 = (float)gp0[t + 512];
  float pf_zm = 0.0f, pf_zl = 0.0f, pf_ep = 0.0f;
  if (zlane) {
    const f16* zp = zx + (size_t)b * 64;
    pf_zm = (float)zp[ze]; pf_zl = (float)zp[32 + ze];
    pf_ep = eps[((size_t)t0 * NB + b) * 32 + ze];
  }

  const uint32_t* myl = lwh + (size_t)t * LDSTR;
  const uint4* whs4 = (const uint4*)whs;

  // ---- preload stream chunk rr=0 for step 0 ----
  uint4 sbuf[13];
  #pragma unroll
  for (int j = 0; j < 13; ++j) sbuf[j] = whs4[j * 256 + t];
  __builtin_amdgcn_sched_barrier(0);

  for (int tl = 0; tl < Tlen; ++tl) {
    const int cur = tl & 1, nxt = cur ^ 1;
    const uint32_t* hu = (const uint32_t*)&hf[cur][0];
    const uint4* hu4 = (const uint4*)hu;

    // ---- phase A: enc row partial (rotated b128 reads), butterfly, z, zu ----
    float ep = 0.0f;
    #pragma unroll
    for (int j = 0; j < 8; ++j) {
      uint4 u4 = hu4[base8 + ((j + rot2) & 7)];
      ep = dot2u(we[4 * j],     u4.x, ep);
      ep = dot2u(we[4 * j + 1], u4.y, ep);
      ep = dot2u(we[4 * j + 2], u4.z, ep);
      ep = dot2u(we[4 * j + 3], u4.w, ep);
    }
    ep += __shfl_xor(ep, 1);
    ep += __shfl_xor(ep, 2);
    float other = __shfl_xor(ep, 32);   // mu lane receives lv row sum
    if (zlane) {
      float z = (pf_zm + ep) + pf_ep * exp2f(0.72134752f * (pf_zl + other));
      ((f16*)zu)[ze] = (f16)z;
    }
    __syncthreads();  // b1: zu visible

    // ---- phase B: gh with pipelined stream ----
    float g0 = 0.0f, g1 = 0.0f, g2 = 0.0f;
    // pairs [0,28): register weights
    #pragma unroll
    for (int g4 = 0; g4 < 7; ++g4) {
      uint4 u4 = hu4[g4];
      g0 = dot2u(wrg[0][4 * g4],     u4.x, g0);
      g1 = dot2u(wrg[1][4 * g4],     u4.x, g1);
      g2 = dot2u(wrg[2][4 * g4],     u4.x, g2);
      g0 = dot2u(wrg[0][4 * g4 + 1], u4.y, g0);
      g1 = dot2u(wrg[1][4 * g4 + 1], u4.y, g1);
      g2 = dot2u(wrg[2][4 * g4 + 1], u4.y, g2);
      g0 = dot2u(wrg[0][4 * g4 + 2], u4.z, g0);
      g1 = dot2u(wrg[1][4 * g4 + 2], u4.z, g1);
      g2 = dot2u(wrg[2][4 * g4 + 2], u4.z, g2);
      g0 = dot2u(wrg[0][4 * g4 + 3], u4.w, g0);
      g1 = dot2u(wrg[1][4 * g4 + 3], u4.w, g1);
      g2 = dot2u(wrg[2][4 * g4 + 3], u4.w, g2);
    }
    // consume stream rr0 (issued last iteration / preload) -> g0; issue rr1
    {
      float a = 0.0f;
      #pragma unroll
      for (int j = 0; j < 13; ++j) {
        uint4 u4 = hu4[19 + j];
        a = dot2u(sbuf[j].x, u4.x, a);
        a = dot2u(sbuf[j].y, u4.y, a);
        a = dot2u(sbuf[j].z, u4.z, a);
        a = dot2u(sbuf[j].w, u4.w, a);
      }
      g0 += a;
    }
    #pragma unroll
    for (int j = 0; j < 13; ++j) sbuf[j] = whs4[(13 + j) * 256 + t];
    __builtin_amdgcn_sched_barrier(0);
    // pairs [28,76) first half: LDS groups 0..5
    #pragma unroll
    for (int g4 = 0; g4 < 6; ++g4) {
      uint4 u4 = hu4[7 + g4];
      uint4 w0 = *(const uint4*)(myl + 0 * LDS_P + 4 * g4);
      uint4 w1 = *(const uint4*)(myl + 1 * LDS_P + 4 * g4);
      uint4 w2 = *(const uint4*)(myl + 2 * LDS_P + 4 * g4);
      g0 = dot2u(w0.x, u4.x, g0); g1 = dot2u(w1.x, u4.x, g1); g2 = dot2u(w2.x, u4.x, g2);
      g0 = dot2u(w0.y, u4.y, g0); g1 = dot2u(w1.y, u4.y, g1); g2 = dot2u(w2.y, u4.y, g2);
      g0 = dot2u(w0.z, u4.z, g0); g1 = dot2u(w1.z, u4.z, g1); g2 = dot2u(w2.z, u4.z, g2);
      g0 = dot2u(w0.w, u4.w, g0); g1 = dot2u(w1.w, u4.w, g1); g2 = dot2u(w2.w, u4.w, g2);
    }
    // consume stream rr1 -> g1; issue rr2
    {
      float a = 0.0f;
      #pragma unroll
      for (int j = 0; j < 13; ++j) {
        uint4 u4 = hu4[19 + j];
        a = dot2u(sbuf[j].x, u4.x, a);
        a = dot2u(sbuf[j].y, u4.y, a);
        a = dot2u(sbuf[j].z, u4.z, a);
        a = dot2u(sbuf[j].w, u4.w, a);
      }
      g1 += a;
    }
    #pragma unroll
    for (int j = 0; j < 13; ++j) sbuf[j] = whs4[(26 + j) * 256 + t];
    __builtin_amdgcn_sched_barrier(0);
    // pairs [28,76) second half: LDS groups 6..11
    #pragma unroll
    for (int g4 = 6; g4 < 12; ++g4) {
      uint4 u4 = hu4[7 + g4];
      uint4 w0 = *(const uint4*)(myl + 0 * LDS_P + 4 * g4);
      uint4 w1 = *(const uint4*)(myl + 1 * LDS_P + 4 * g4);
      uint4 w2 = *(const uint4*)(myl + 2 * LDS_P + 4 * g4);
      g0 = dot2u(w0.x, u4.x, g0); g1 = dot2u(w1.x, u4.x, g1); g2 = dot2u(w2.x, u4.x, g2);
      g0 = dot2u(w0.y, u4.y, g0); g1 = dot2u(w1.y, u4.y, g1); g2 = dot2u(w2.y, u4.y, g2);
      g0 = dot2u(w0.z, u4.z, g0); g1 = dot2u(w1.z, u4.z, g1); g2 = dot2u(w2.z, u4.z, g2);
      g0 = dot2u(w0.w, u4.w, g0); g1 = dot2u(w1.w, u4.w, g1); g2 = dot2u(w2.w, u4.w, g2);
    }
    // consume stream rr2 -> g2
    {
      float a = 0.0f;
      #pragma unroll
      for (int j = 0; j < 13; ++j) {
        uint4 u4 = hu4[19 + j];
        a = dot2u(sbuf[j].x, u4.x, a);
        a = dot2u(sbuf[j].y, u4.y, a);
        a = dot2u(sbuf[j].z, u4.z, a);
        a = dot2u(sbuf[j].w, u4.w, a);
      }
      g2 += a;
    }

    // ---- gates: gi_z from broadcast z (zu visible since b1) ----
    float q0 = 0.0f, q1 = 0.0f, q2 = 0.0f;
    #pragma unroll
    for (int p = 0; p < 16; ++p) {
      uint32_t u = zu[p];          // broadcast reads
      q0 = dot2u(wz[0][p], u, q0);
      q1 = dot2u(wz[1][p], u, q1);
      q2 = dot2u(wz[2][p], u, q2);
    }
    float r  = sigm(pf_g0 + g0 + q0);
    float uu = sigm(pf_g1 + g1 + q1);
    float n  = tanh_f(pf_g2 + q2 + r * (g2 + bhn));
    hm = (1.0f - uu) * n + uu * hm;
    hf[nxt][t] = (f16)hm;

    // ---- issue stream rr0 for NEXT step ----
    #pragma unroll
    for (int j = 0; j < 13; ++j) sbuf[j] = whs4[j * 256 + t];
    __builtin_amdgcn_sched_barrier(0);

    // ---- prefetch activation streams for tl+1 ----
    int tn = (tl + 1 < Tlen) ? tl + 1 : tl;
    const f16* gp = gix + ((size_t)tn * NB + b) * 768;
    pf_g0 = (float)gp[t]; pf_g1 = (float)gp[t + 256]; pf_g2 = (float)gp[t + 512];
    if (zlane) {
      const f16* zp = zx + ((size_t)tn * NB + b) * 64;
      pf_zm = (float)zp[ze]; pf_zl = (float)zp[32 + ze];
      pf_ep = eps[((size_t)(t0 + tn) * NB + b) * 32 + ze];
    }
    __syncthreads();  // b2: h_new visible
  }

  if (last) out[b * 256 + t] = hm;
  else      hws[b * 256 + t] = hm;
}

extern "C" void kernel_launch(void* const* d_in, const int* in_sizes, int n_in,
                              void* d_out, int out_size, void* d_ws, size_t ws_size,
                              hipStream_t stream) {
  const float* x    = (const float*)d_in[0];
  const float* eps  = (const float*)d_in[1];
  const float* emW  = (const float*)d_in[2];
  const float* emb  = (const float*)d_in[3];
  const float* esW  = (const float*)d_in[4];
  const float* esb  = (const float*)d_in[5];
  const float* W_ih = (const float*)d_in[10];
  const float* W_hh = (const float*)d_in[11];
  const float* b_ih = (const float*)d_in[12];
  const float* b_hh = (const float*)d_in[13];
  float* out = (float*)d_out;

  // workspace layout (16B-aligned regions)
  const size_t o_whr = 262144;                  // hws: 256 KB
  const size_t o_whl = o_whr + 86016;           // whr: 21*256*16
  const size_t o_whs = o_whl + 151552;          // whl: 148*256*4
  const size_t o_whz = o_whs + 159744;          // whs: 39*256*16
  const size_t o_wep = o_whz + 49152;           // whz: 12*256*16
  const size_t o_gix = o_wep + 32768;           // wep: 8*256*16  -> 741,376
  int Tc = TSEQ;
  while (Tc > 8 && o_gix + (size_t)Tc * NB * (768 + 64) * 2 > ws_size) Tc >>= 1;

  float*    hws   = (float*)d_ws;
  uint32_t* whr   = (uint32_t*)((char*)d_ws + o_whr);
  uint32_t* whl_g = (uint32_t*)((char*)d_ws + o_whl);
  uint32_t* whs   = (uint32_t*)((char*)d_ws + o_whs);
  uint32_t* whz   = (uint32_t*)((char*)d_ws + o_whz);
  uint32_t* wep   = (uint32_t*)((char*)d_ws + o_wep);
  f16*      gix   = (f16*)((char*)d_ws + o_gix);
  f16*      zx    = gix + (size_t)Tc * NB * 768;

  vrnn_pack<<<dim3(1), dim3(256), 0, stream>>>(W_hh, W_ih, emW, esW,
                                               whr, whl_g, whs, whz, wep);

  int nch = TSEQ / Tc;
  int TT  = Tc < 64 ? Tc : 64;
  int nTT = Tc / TT;

  for (int c = 0; c < nch; ++c) {
    vrnn_pre<<<dim3(NB * nTT), dim3(256), 0, stream>>>(
        x, W_ih, b_ih, b_hh, emW, emb, esW, esb, gix, zx, c * Tc, TT, nTT);
    vrnn_rec<<<dim3(NB), dim3(256), 0, stream>>>(
        gix, zx, eps, whr, whl_g, whs, whz, wep, b_hh, hws, out,
        c * Tc, Tc, c == 0 ? 1 : 0, c == nch - 1 ? 1 : 0);
  }
}

// Round 19
// 2821.837 us; speedup vs baseline: 1.4602x; 1.1594x over previous
//
#include <hip/hip_runtime.h>
#include <stdint.h>

#define NB 256      // batch
#define TSEQ 1024   // sequence length
#define TT_MAX 64

// v10: 512 threads, K split between lane pairs. Per HALF-row (64 pairs):
#define REG_P 12    // pairs in registers (3*12 = 36 VGPRs)
#define LDS_P 24    // pairs in LDS (3*24 = 72 u32/thread)
#define STR_P 28    // pairs streamed from L2 (3*7 uint4)
#define LDSTR 76    // u32 stride of per-thread LDS slice (16B-aligned; bank walk 12t%32)

typedef _Float16 f16;
typedef _Float16 h2 __attribute__((ext_vector_type(2)));

static __device__ __forceinline__ uint32_t pkh2(float a, float b) {
  h2 v; v[0] = (f16)a; v[1] = (f16)b;
  return __builtin_bit_cast(uint32_t, v);
}

#if __has_builtin(__builtin_amdgcn_fdot2)
static __device__ __forceinline__ float dot2u(uint32_t w, uint32_t h, float c) {
  return __builtin_amdgcn_fdot2(__builtin_bit_cast(h2, w), __builtin_bit_cast(h2, h), c, false);
}
#else
static __device__ __forceinline__ float dot2u(uint32_t w, uint32_t h, float c) {
  h2 a = __builtin_bit_cast(h2, w), b = __builtin_bit_cast(h2, h);
  return c + (float)a[0] * (float)b[0] + (float)a[1] * (float)b[1];
}
#endif

#if __has_builtin(__builtin_amdgcn_rcpf)
#define RCPF(x) __builtin_amdgcn_rcpf(x)
#else
#define RCPF(x) (1.0f / (x))
#endif

static __device__ __forceinline__ float sigm(float x) {
  return RCPF(1.0f + exp2f(-1.44269504f * x));
}
static __device__ __forceinline__ float tanh_f(float x) {
  return 1.0f - 2.0f * RCPF(1.0f + exp2f(2.88539008f * x));
}

// ---------------------------------------------------------------------------
// One-time weight pack (f16), 512-thread consumer layout.
// Thread t: row r=t>>1, k-half q=t&1 (f16-pairs [64q, 64q+64) of each row).
//  whr : [(rr*3+cj)*512 + t] uint4, half-pairs [0,12)
//  whl : [t*LDSTR + rr*24 + p],     half-pairs [12,36)
//  whs : [(rr*7+j)*512 + t] uint4,  half-pairs [36,64)
//  whz : [(rr*2+cj)*512 + t] uint4, z-pairs [8q, 8q+8)
//  wep : [p4*512 + t] uint4 — enc row e=t&63, k-slice s=t>>6 (16 pairs)
// ---------------------------------------------------------------------------
__global__ __launch_bounds__(512) void vrnn_pack(
    const float* __restrict__ W_hh, const float* __restrict__ W_ih,
    const float* __restrict__ emW, const float* __restrict__ esW,
    uint32_t* __restrict__ whr, uint32_t* __restrict__ whl,
    uint32_t* __restrict__ whs, uint32_t* __restrict__ whz,
    uint32_t* __restrict__ wep)
{
  const int t = threadIdx.x;
  const int r = t >> 1, q = t & 1;
  for (int rr = 0; rr < 3; ++rr) {
    const float* R = W_hh + (size_t)(r + rr * 256) * 256 + q * 128;
    for (int cj = 0; cj < 3; ++cj)
      for (int i = 0; i < 4; ++i) {
        int p = cj * 4 + i;
        whr[(((size_t)rr * 3 + cj) * 512 + t) * 4 + i] = pkh2(R[2 * p], R[2 * p + 1]);
      }
    for (int p = 0; p < LDS_P; ++p)
      whl[(size_t)t * LDSTR + rr * LDS_P + p] = pkh2(R[2 * (p + REG_P)], R[2 * (p + REG_P) + 1]);
    for (int j = 0; j < 7; ++j)
      for (int i = 0; i < 4; ++i) {
        int p = 36 + j * 4 + i;
        whs[(((size_t)rr * 7 + j) * 512 + t) * 4 + i] = pkh2(R[2 * p], R[2 * p + 1]);
      }
    const float* Z = W_ih + (size_t)(r + rr * 256) * 96 + 64 + q * 16;
    for (int cj = 0; cj < 2; ++cj)
      for (int i = 0; i < 4; ++i) {
        int p = cj * 4 + i;
        whz[(((size_t)rr * 2 + cj) * 512 + t) * 4 + i] = pkh2(Z[2 * p], Z[2 * p + 1]);
      }
  }
  {
    const int e = t & 63, s = t >> 6;
    const float* esrc = (e < 32) ? (emW + (size_t)e * 320 + 64)
                                 : (esW + (size_t)(e - 32) * 320 + 64);
    for (int p4 = 0; p4 < 4; ++p4)
      for (int i = 0; i < 4; ++i) {
        int pc = s * 16 + p4 * 4 + i;
        wep[((size_t)p4 * 512 + t) * 4 + i] = pkh2(esrc[2 * pc], esrc[2 * pc + 1]);
      }
  }
}

// ---------------------------------------------------------------------------
// Precompute kernel (unchanged): gi_x'[t][b][768], zx'[t][b][64]
// ---------------------------------------------------------------------------
__global__ __launch_bounds__(256, 2) void vrnn_pre(
    const float* __restrict__ x, const float* __restrict__ W_ih,
    const float* __restrict__ b_ih, const float* __restrict__ b_hh,
    const float* __restrict__ emW, const float* __restrict__ emb,
    const float* __restrict__ esW, const float* __restrict__ esb,
    f16* __restrict__ gix, f16* __restrict__ zx,
    int chunk_t0, int TT, int nTT)
{
  const int tid = threadIdx.x;
  const int b  = blockIdx.x / nTT;
  const int tt = blockIdx.x % nTT;
  const int tloc0 = tt * TT;

  uint32_t wx[3][32];
  float bias[3];
  #pragma unroll
  for (int rr = 0; rr < 3; ++rr) {
    int j = tid + rr * 256;
    const float4* wr = (const float4*)(W_ih + (size_t)j * 96);
    #pragma unroll
    for (int p4 = 0; p4 < 16; ++p4) {
      float4 v = wr[p4];
      wx[rr][2 * p4]     = pkh2(v.x, v.y);
      wx[rr][2 * p4 + 1] = pkh2(v.z, v.w);
    }
    bias[rr] = b_ih[j] + (rr < 2 ? b_hh[j] : 0.0f);  // fold b_hh into r,z rows only
  }
  uint32_t we[32]; float ebias = 0.0f;
  if (tid < 64) {
    const float* src = (tid < 32) ? (emW + (size_t)tid * 320)
                                  : (esW + (size_t)(tid - 32) * 320);
    #pragma unroll
    for (int p = 0; p < 32; ++p) we[p] = pkh2(src[2 * p], src[2 * p + 1]);
    ebias = (tid < 32) ? emb[tid] : esb[tid - 32];
  }

  __shared__ uint32_t xs[TT_MAX * 32];
  for (int idx = tid; idx < TT * 32; idx += 256) {
    int tl = idx >> 5, pk = idx & 31;
    size_t base = ((size_t)b * TSEQ + (chunk_t0 + tloc0 + tl)) * 64 + 2 * pk;
    xs[idx] = pkh2(x[base], x[base + 1]);
  }
  __syncthreads();

  for (int tl = 0; tl < TT; ++tl) {
    float a0 = bias[0], a1 = bias[1], a2 = bias[2];
    #pragma unroll
    for (int p = 0; p < 32; ++p) {
      uint32_t u = xs[tl * 32 + p];
      a0 = dot2u(wx[0][p], u, a0);
      a1 = dot2u(wx[1][p], u, a1);
      a2 = dot2u(wx[2][p], u, a2);
    }
    size_t ob = (size_t)(tloc0 + tl) * NB + b;
    f16* g = gix + ob * 768;
    g[tid] = (f16)a0; g[tid + 256] = (f16)a1; g[tid + 512] = (f16)a2;
    if (tid < 64) {
      float a3 = ebias;
      #pragma unroll
      for (int p = 0; p < 32; ++p) a3 = dot2u(we[p], xs[tl * 32 + p], a3);
      zx[ob * 64 + tid] = (f16)a3;
    }
  }
}

// ---------------------------------------------------------------------------
// Recurrent kernel v10: 512 threads (8 waves, 2/SIMD), one batch per block.
// R14/R17 post-mortem: at 1 wave/SIMD (256 thr) every L2/LDS/dep latency is
// exposed (step 6330cyc vs ~1400 of issue); barrier-count tweaks are noise.
// Fix occupancy: lane pair (2i,2i+1) owns row i's two K-halves; 2 waves/SIMD.
// Budget = 128 VGPR (512-thr rule, R1/R6): wrg 36 + wz 24 + we 16 + sbuf 28
// pinned + ~20 live = fits. Same 3-stage pipelined L2 stream, 3 barriers.
// Gates: 6x shfl_xor(1) pair-reduce, even lanes finalize + write.
// ---------------------------------------------------------------------------
__global__ __launch_bounds__(512) void vrnn_rec(
    const f16* __restrict__ gix, const f16* __restrict__ zx,
    const float* __restrict__ eps,
    const uint32_t* __restrict__ whr, const uint32_t* __restrict__ whl_g,
    const uint32_t* __restrict__ whs, const uint32_t* __restrict__ whz,
    const uint32_t* __restrict__ wep_g,
    const float* __restrict__ b_hh,
    float* __restrict__ hws, float* __restrict__ out,
    int t0, int Tlen, int first, int last)
{
  const int t = threadIdx.x;
  const int b = blockIdx.x;
  const int r = t >> 1, q = t & 1;

  // ---- pinned register weights ----
  uint32_t wrg[3][REG_P];              // 36
  {
    const uint4* w4 = (const uint4*)whr;
    #pragma unroll
    for (int c = 0; c < 9; ++c) {
      uint4 v = w4[c * 512 + t];
      int rr = c / 3, p4 = c % 3;
      wrg[rr][4 * p4] = v.x; wrg[rr][4 * p4 + 1] = v.y;
      wrg[rr][4 * p4 + 2] = v.z; wrg[rr][4 * p4 + 3] = v.w;
    }
  }
  uint32_t wz[3][8];                   // 24
  {
    const uint4* w4 = (const uint4*)whz;
    #pragma unroll
    for (int c = 0; c < 6; ++c) {
      uint4 v = w4[c * 512 + t];
      int rr = c / 2, p4 = c % 2;
      wz[rr][4 * p4] = v.x; wz[rr][4 * p4 + 1] = v.y;
      wz[rr][4 * p4 + 2] = v.z; wz[rr][4 * p4 + 3] = v.w;
    }
  }
  uint32_t we[16];                     // 16
  {
    const uint4* w4 = (const uint4*)wep_g;
    #pragma unroll
    for (int c = 0; c < 4; ++c) {
      uint4 v = w4[c * 512 + t];
      we[4 * c] = v.x; we[4 * c + 1] = v.y; we[4 * c + 2] = v.z; we[4 * c + 3] = v.w;
    }
  }
  #pragma unroll
  for (int rr = 0; rr < 3; ++rr) {
    #pragma unroll
    for (int i = 0; i < REG_P; ++i) asm volatile("" : "+v"(wrg[rr][i]));
    #pragma unroll
    for (int i = 0; i < 8; ++i)    asm volatile("" : "+v"(wz[rr][i]));
  }
  #pragma unroll
  for (int i = 0; i < 16; ++i) asm volatile("" : "+v"(we[i]));
  const float bhn = b_hh[512 + r];

  // ---- LDS (~158.8 KB) ----
  __shared__ uint32_t lwh[512 * LDSTR];          // 155,648 B
  __shared__ __align__(16) f16 hf[2][256];
  __shared__ float encp[512];
  __shared__ uint32_t zu[16];

  {
    const uint4* src = (const uint4*)(whl_g + (size_t)t * LDSTR);
    uint4* dst = (uint4*)(lwh + (size_t)t * LDSTR);
    #pragma unroll
    for (int j = 0; j < LDSTR / 4; ++j) dst[j] = src[j];
  }

  float hm = 0.0f;
  if (!q) {
    hm = first ? 0.0f : hws[b * 256 + r];
    hf[0][r] = (f16)hm;
  }
  __syncthreads();   // once, outside the loop

  // ---- stream prefetch for t=0 ----
  float pf_g0 = 0.0f, pf_g1 = 0.0f, pf_g2 = 0.0f;
  if (!q) {
    const f16* gp0 = gix + (size_t)b * 768;
    pf_g0 = (float)gp0[r]; pf_g1 = (float)gp0[r + 256]; pf_g2 = (float)gp0[r + 512];
  }
  float pf_zm = 0.0f, pf_zl = 0.0f, pf_ep = 0.0f;
  if (t < 32) {
    const f16* zp = zx + (size_t)b * 64;
    pf_zm = (float)zp[t]; pf_zl = (float)zp[32 + t];
    pf_ep = eps[((size_t)t0 * NB + b) * 32 + t];
  }

  const int s = t >> 6;                      // wave id (phase-A k-slice)
  const int bq = q * 16;                     // hu4 base of this thread's k-half
  const uint32_t* myl = lwh + (size_t)t * LDSTR;
  const uint4* whs4 = (const uint4*)whs;

  // ---- preload stream chunk rr=0 for step 0 ----
  uint4 sbuf[7];
  #pragma unroll
  for (int j = 0; j < 7; ++j) sbuf[j] = whs4[j * 512 + t];
  __builtin_amdgcn_sched_barrier(0);

  for (int tl = 0; tl < Tlen; ++tl) {
    const int cur = tl & 1, nxt = cur ^ 1;
    const uint32_t* hu = (const uint32_t*)&hf[cur][0];
    const uint4* hu4 = (const uint4*)hu;

    // ---- phase A: encoder partials (wave-uniform h slice s) ----
    float ep_ = 0.0f;
    #pragma unroll
    for (int p4 = 0; p4 < 4; ++p4) {
      uint4 u4 = hu4[s * 4 + p4];
      ep_ = dot2u(we[4 * p4],     u4.x, ep_);
      ep_ = dot2u(we[4 * p4 + 1], u4.y, ep_);
      ep_ = dot2u(we[4 * p4 + 2], u4.z, ep_);
      ep_ = dot2u(we[4 * p4 + 3], u4.w, ep_);
    }
    encp[t] = ep_;
    __syncthreads();  // b1

    // ---- phase B: z (32 threads) || gh (all threads, own k-half) ----
    if (t < 32) {
      float mu = pf_zm, lv = pf_zl;
      #pragma unroll
      for (int ss = 0; ss < 8; ++ss) {
        mu += encp[ss * 64 + t];
        lv += encp[ss * 64 + 32 + t];
      }
      float z = mu + pf_ep * exp2f(0.72134752f * lv);   // mu + eps*exp(0.5*lv)
      ((f16*)zu)[t] = (f16)z;
    }
    float g0 = 0.0f, g1 = 0.0f, g2 = 0.0f;
    // half-pairs [0,12): register weights
    #pragma unroll
    for (int g4 = 0; g4 < 3; ++g4) {
      uint4 u4 = hu4[bq + g4];
      g0 = dot2u(wrg[0][4 * g4],     u4.x, g0);
      g1 = dot2u(wrg[1][4 * g4],     u4.x, g1);
      g2 = dot2u(wrg[2][4 * g4],     u4.x, g2);
      g0 = dot2u(wrg[0][4 * g4 + 1], u4.y, g0);
      g1 = dot2u(wrg[1][4 * g4 + 1], u4.y, g1);
      g2 = dot2u(wrg[2][4 * g4 + 1], u4.y, g2);
      g0 = dot2u(wrg[0][4 * g4 + 2], u4.z, g0);
      g1 = dot2u(wrg[1][4 * g4 + 2], u4.z, g1);
      g2 = dot2u(wrg[2][4 * g4 + 2], u4.z, g2);
      g0 = dot2u(wrg[0][4 * g4 + 3], u4.w, g0);
      g1 = dot2u(wrg[1][4 * g4 + 3], u4.w, g1);
      g2 = dot2u(wrg[2][4 * g4 + 3], u4.w, g2);
    }
    // consume stream rr0 (half-pairs [36,64)) -> g0; issue rr1
    {
      float a = 0.0f;
      #pragma unroll
      for (int j = 0; j < 7; ++j) {
        uint4 u4 = hu4[bq + 9 + j];
        a = dot2u(sbuf[j].x, u4.x, a);
        a = dot2u(sbuf[j].y, u4.y, a);
        a = dot2u(sbuf[j].z, u4.z, a);
        a = dot2u(sbuf[j].w, u4.w, a);
      }
      g0 += a;
    }
    #pragma unroll
    for (int j = 0; j < 7; ++j) sbuf[j] = whs4[(7 + j) * 512 + t];
    __builtin_amdgcn_sched_barrier(0);
    // half-pairs [12,36) first half: LDS groups 0..2
    #pragma unroll
    for (int g4 = 0; g4 < 3; ++g4) {
      uint4 u4 = hu4[bq + 3 + g4];
      uint4 w0 = *(const uint4*)(myl + 0 * LDS_P + 4 * g4);
      uint4 w1 = *(const uint4*)(myl + 1 * LDS_P + 4 * g4);
      uint4 w2 = *(const uint4*)(myl + 2 * LDS_P + 4 * g4);
      g0 = dot2u(w0.x, u4.x, g0); g1 = dot2u(w1.x, u4.x, g1); g2 = dot2u(w2.x, u4.x, g2);
      g0 = dot2u(w0.y, u4.y, g0); g1 = dot2u(w1.y, u4.y, g1); g2 = dot2u(w2.y, u4.y, g2);
      g0 = dot2u(w0.z, u4.z, g0); g1 = dot2u(w1.z, u4.z, g1); g2 = dot2u(w2.z, u4.z, g2);
      g0 = dot2u(w0.w, u4.w, g0); g1 = dot2u(w1.w, u4.w, g1); g2 = dot2u(w2.w, u4.w, g2);
    }
    // consume stream rr1 -> g1; issue rr2
    {
      float a = 0.0f;
      #pragma unroll
      for (int j = 0; j < 7; ++j) {
        uint4 u4 = hu4[bq + 9 + j];
        a = dot2u(sbuf[j].x, u4.x, a);
        a = dot2u(sbuf[j].y, u4.y, a);
        a = dot2u(sbuf[j].z, u4.z, a);
        a = dot2u(sbuf[j].w, u4.w, a);
      }
      g1 += a;
    }
    #pragma unroll
    for (int j = 0; j < 7; ++j) sbuf[j] = whs4[(14 + j) * 512 + t];
    __builtin_amdgcn_sched_barrier(0);
    // half-pairs [12,36) second half: LDS groups 3..5
    #pragma unroll
    for (int g4 = 3; g4 < 6; ++g4) {
      uint4 u4 = hu4[bq + 3 + g4];
      uint4 w0 = *(const uint4*)(myl + 0 * LDS_P + 4 * g4);
      uint4 w1 = *(const uint4*)(myl + 1 * LDS_P + 4 * g4);
      uint4 w2 = *(const uint4*)(myl + 2 * LDS_P + 4 * g4);
      g0 = dot2u(w0.x, u4.x, g0); g1 = dot2u(w1.x, u4.x, g1); g2 = dot2u(w2.x, u4.x, g2);
      g0 = dot2u(w0.y, u4.y, g0); g1 = dot2u(w1.y, u4.y, g1); g2 = dot2u(w2.y, u4.y, g2);
      g0 = dot2u(w0.z, u4.z, g0); g1 = dot2u(w1.z, u4.z, g1); g2 = dot2u(w2.z, u4.z, g2);
      g0 = dot2u(w0.w, u4.w, g0); g1 = dot2u(w1.w, u4.w, g1); g2 = dot2u(w2.w, u4.w, g2);
    }
    // consume stream rr2 -> g2
    {
      float a = 0.0f;
      #pragma unroll
      for (int j = 0; j < 7; ++j) {
        uint4 u4 = hu4[bq + 9 + j];
        a = dot2u(sbuf[j].x, u4.x, a);
        a = dot2u(sbuf[j].y, u4.y, a);
        a = dot2u(sbuf[j].z, u4.z, a);
        a = dot2u(sbuf[j].w, u4.w, a);
      }
      g2 += a;
    }
    __syncthreads();  // b2  (zu visible)

    // ---- phase C: gi_z (own 8 z-pairs), pair-reduce, gates (even lanes) ----
    float q0 = 0.0f, q1 = 0.0f, q2 = 0.0f;
    #pragma unroll
    for (int p = 0; p < 8; ++p) {
      uint32_t u = zu[q * 8 + p];    // broadcast reads
      q0 = dot2u(wz[0][p], u, q0);
      q1 = dot2u(wz[1][p], u, q1);
      q2 = dot2u(wz[2][p], u, q2);
    }
    g0 += __shfl_xor(g0, 1); g1 += __shfl_xor(g1, 1); g2 += __shfl_xor(g2, 1);
    q0 += __shfl_xor(q0, 1); q1 += __shfl_xor(q1, 1); q2 += __shfl_xor(q2, 1);
    if (!q) {
      float rg = sigm(pf_g0 + g0 + q0);
      float uu = sigm(pf_g1 + g1 + q1);
      float n  = tanh_f(pf_g2 + q2 + rg * (g2 + bhn));
      hm = (1.0f - uu) * n + uu * hm;
      hf[nxt][r] = (f16)hm;
    }

    // ---- issue stream rr0 for NEXT step ----
    #pragma unroll
    for (int j = 0; j < 7; ++j) sbuf[j] = whs4[j * 512 + t];
    __builtin_amdgcn_sched_barrier(0);

    // ---- prefetch activation streams for tl+1 ----
    int tn = (tl + 1 < Tlen) ? tl + 1 : tl;
    if (!q) {
      const f16* gp = gix + ((size_t)tn * NB + b) * 768;
      pf_g0 = (float)gp[r]; pf_g1 = (float)gp[r + 256]; pf_g2 = (float)gp[r + 512];
    }
    if (t < 32) {
      const f16* zp = zx + ((size_t)tn * NB + b) * 64;
      pf_zm = (float)zp[t]; pf_zl = (float)zp[32 + t];
      pf_ep = eps[((size_t)(t0 + tn) * NB + b) * 32 + t];
    }
    __syncthreads();  // b3  (h_new visible)
  }

  if (!q) {
    if (last) out[b * 256 + r] = hm;
    else      hws[b * 256 + r] = hm;
  }
}

extern "C" void kernel_launch(void* const* d_in, const int* in_sizes, int n_in,
                              void* d_out, int out_size, void* d_ws, size_t ws_size,
                              hipStream_t stream) {
  const float* x    = (const float*)d_in[0];
  const float* eps  = (const float*)d_in[1];
  const float* emW  = (const float*)d_in[2];
  const float* emb  = (const float*)d_in[3];
  const float* esW  = (const float*)d_in[4];
  const float* esb  = (const float*)d_in[5];
  const float* W_ih = (const float*)d_in[10];
  const float* W_hh = (const float*)d_in[11];
  const float* b_ih = (const float*)d_in[12];
  const float* b_hh = (const float*)d_in[13];
  float* out = (float*)d_out;

  // workspace layout (16B-aligned regions)
  const size_t o_whr = 262144;                  // hws: 256 KB
  const size_t o_whl = o_whr + 73728;           // whr: 9*512*16
  const size_t o_whs = o_whl + 155648;          // whl: 76*512*4
  const size_t o_whz = o_whs + 172032;          // whs: 21*512*16
  const size_t o_wep = o_whz + 49152;           // whz: 6*512*16
  const size_t o_gix = o_wep + 32768;           // wep: 4*512*16  -> 745,472
  int Tc = TSEQ;
  while (Tc > 8 && o_gix + (size_t)Tc * NB * (768 + 64) * 2 > ws_size) Tc >>= 1;

  float*    hws   = (float*)d_ws;
  uint32_t* whr   = (uint32_t*)((char*)d_ws + o_whr);
  uint32_t* whl_g = (uint32_t*)((char*)d_ws + o_whl);
  uint32_t* whs   = (uint32_t*)((char*)d_ws + o_whs);
  uint32_t* whz   = (uint32_t*)((char*)d_ws + o_whz);
  uint32_t* wep   = (uint32_t*)((char*)d_ws + o_wep);
  f16*      gix   = (f16*)((char*)d_ws + o_gix);
  f16*      zx    = gix + (size_t)Tc * NB * 768;

  vrnn_pack<<<dim3(1), dim3(512), 0, stream>>>(W_hh, W_ih, emW, esW,
                                               whr, whl_g, whs, whz, wep);

  int nch = TSEQ / Tc;
  int TT  = Tc < 64 ? Tc : 64;
  int nTT = Tc / TT;

  for (int c = 0; c < nch; ++c) {
    vrnn_pre<<<dim3(NB * nTT), dim3(256), 0, stream>>>(
        x, W_ih, b_ih, b_hh, emW, emb, esW, esb, gix, zx, c * Tc, TT, nTT);
    vrnn_rec<<<dim3(NB), dim3(512), 0, stream>>>(
        gix, zx, eps, whr, whl_g, whs, whz, wep, b_hh, hws, out,
        c * Tc, Tc, c == 0 ? 1 : 0, c == nch - 1 ? 1 : 0);
  }
}

// Round 20
// 2623.151 us; speedup vs baseline: 1.5708x; 1.0757x over previous
//
#include <hip/hip_runtime.h>
#include <stdint.h>

#define NB 256      // batch
#define TSEQ 1024   // sequence length
#define TT_MAX 64

// v10.1: 512 threads, K split between lane pairs. Per HALF-row (64 pairs):
#define REG_P 12    // pairs in registers (3*12 = 36 VGPRs)
#define LDS_P 24    // pairs in LDS (3*24 = 72 u32/thread)
#define STR_P 28    // pairs streamed from L2 (3*7 uint4)
#define LDSTR 76    // u32 stride of per-thread LDS slice

typedef _Float16 f16;
typedef _Float16 h2 __attribute__((ext_vector_type(2)));

static __device__ __forceinline__ uint32_t pkh2(float a, float b) {
  h2 v; v[0] = (f16)a; v[1] = (f16)b;
  return __builtin_bit_cast(uint32_t, v);
}

#if __has_builtin(__builtin_amdgcn_fdot2)
static __device__ __forceinline__ float dot2u(uint32_t w, uint32_t h, float c) {
  return __builtin_amdgcn_fdot2(__builtin_bit_cast(h2, w), __builtin_bit_cast(h2, h), c, false);
}
#else
static __device__ __forceinline__ float dot2u(uint32_t w, uint32_t h, float c) {
  h2 a = __builtin_bit_cast(h2, w), b = __builtin_bit_cast(h2, h);
  return c + (float)a[0] * (float)b[0] + (float)a[1] * (float)b[1];
}
#endif

#if __has_builtin(__builtin_amdgcn_rcpf)
#define RCPF(x) __builtin_amdgcn_rcpf(x)
#else
#define RCPF(x) (1.0f / (x))
#endif

static __device__ __forceinline__ float sigm(float x) {
  return RCPF(1.0f + exp2f(-1.44269504f * x));
}
static __device__ __forceinline__ float tanh_f(float x) {
  return 1.0f - 2.0f * RCPF(1.0f + exp2f(2.88539008f * x));
}

// ---------------------------------------------------------------------------
// One-time weight pack (f16), 512-thread consumer layout (unchanged from v10).
// Thread t: row r=t>>1, k-half q=t&1 (f16-pairs [64q, 64q+64) of each row).
// ---------------------------------------------------------------------------
__global__ __launch_bounds__(512) void vrnn_pack(
    const float* __restrict__ W_hh, const float* __restrict__ W_ih,
    const float* __restrict__ emW, const float* __restrict__ esW,
    uint32_t* __restrict__ whr, uint32_t* __restrict__ whl,
    uint32_t* __restrict__ whs, uint32_t* __restrict__ whz,
    uint32_t* __restrict__ wep)
{
  const int t = threadIdx.x;
  const int r = t >> 1, q = t & 1;
  for (int rr = 0; rr < 3; ++rr) {
    const float* R = W_hh + (size_t)(r + rr * 256) * 256 + q * 128;
    for (int cj = 0; cj < 3; ++cj)
      for (int i = 0; i < 4; ++i) {
        int p = cj * 4 + i;
        whr[(((size_t)rr * 3 + cj) * 512 + t) * 4 + i] = pkh2(R[2 * p], R[2 * p + 1]);
      }
    for (int p = 0; p < LDS_P; ++p)
      whl[(size_t)t * LDSTR + rr * LDS_P + p] = pkh2(R[2 * (p + REG_P)], R[2 * (p + REG_P) + 1]);
    for (int j = 0; j < 7; ++j)
      for (int i = 0; i < 4; ++i) {
        int p = 36 + j * 4 + i;
        whs[(((size_t)rr * 7 + j) * 512 + t) * 4 + i] = pkh2(R[2 * p], R[2 * p + 1]);
      }
    const float* Z = W_ih + (size_t)(r + rr * 256) * 96 + 64 + q * 16;
    for (int cj = 0; cj < 2; ++cj)
      for (int i = 0; i < 4; ++i) {
        int p = cj * 4 + i;
        whz[(((size_t)rr * 2 + cj) * 512 + t) * 4 + i] = pkh2(Z[2 * p], Z[2 * p + 1]);
      }
  }
  {
    const int e = t & 63, s = t >> 6;
    const float* esrc = (e < 32) ? (emW + (size_t)e * 320 + 64)
                                 : (esW + (size_t)(e - 32) * 320 + 64);
    for (int p4 = 0; p4 < 4; ++p4)
      for (int i = 0; i < 4; ++i) {
        int pc = s * 16 + p4 * 4 + i;
        wep[((size_t)p4 * 512 + t) * 4 + i] = pkh2(esrc[2 * pc], esrc[2 * pc + 1]);
      }
  }
}

// ---------------------------------------------------------------------------
// Precompute kernel (unchanged): gi_x'[t][b][768], zx'[t][b][64]
// ---------------------------------------------------------------------------
__global__ __launch_bounds__(256, 2) void vrnn_pre(
    const float* __restrict__ x, const float* __restrict__ W_ih,
    const float* __restrict__ b_ih, const float* __restrict__ b_hh,
    const float* __restrict__ emW, const float* __restrict__ emb,
    const float* __restrict__ esW, const float* __restrict__ esb,
    f16* __restrict__ gix, f16* __restrict__ zx,
    int chunk_t0, int TT, int nTT)
{
  const int tid = threadIdx.x;
  const int b  = blockIdx.x / nTT;
  const int tt = blockIdx.x % nTT;
  const int tloc0 = tt * TT;

  uint32_t wx[3][32];
  float bias[3];
  #pragma unroll
  for (int rr = 0; rr < 3; ++rr) {
    int j = tid + rr * 256;
    const float4* wr = (const float4*)(W_ih + (size_t)j * 96);
    #pragma unroll
    for (int p4 = 0; p4 < 16; ++p4) {
      float4 v = wr[p4];
      wx[rr][2 * p4]     = pkh2(v.x, v.y);
      wx[rr][2 * p4 + 1] = pkh2(v.z, v.w);
    }
    bias[rr] = b_ih[j] + (rr < 2 ? b_hh[j] : 0.0f);  // fold b_hh into r,z rows only
  }
  uint32_t we[32]; float ebias = 0.0f;
  if (tid < 64) {
    const float* src = (tid < 32) ? (emW + (size_t)tid * 320)
                                  : (esW + (size_t)(tid - 32) * 320);
    #pragma unroll
    for (int p = 0; p < 32; ++p) we[p] = pkh2(src[2 * p], src[2 * p + 1]);
    ebias = (tid < 32) ? emb[tid] : esb[tid - 32];
  }

  __shared__ uint32_t xs[TT_MAX * 32];
  for (int idx = tid; idx < TT * 32; idx += 256) {
    int tl = idx >> 5, pk = idx & 31;
    size_t base = ((size_t)b * TSEQ + (chunk_t0 + tloc0 + tl)) * 64 + 2 * pk;
    xs[idx] = pkh2(x[base], x[base + 1]);
  }
  __syncthreads();

  for (int tl = 0; tl < TT; ++tl) {
    float a0 = bias[0], a1 = bias[1], a2 = bias[2];
    #pragma unroll
    for (int p = 0; p < 32; ++p) {
      uint32_t u = xs[tl * 32 + p];
      a0 = dot2u(wx[0][p], u, a0);
      a1 = dot2u(wx[1][p], u, a1);
      a2 = dot2u(wx[2][p], u, a2);
    }
    size_t ob = (size_t)(tloc0 + tl) * NB + b;
    f16* g = gix + ob * 768;
    g[tid] = (f16)a0; g[tid + 256] = (f16)a1; g[tid + 512] = (f16)a2;
    if (tid < 64) {
      float a3 = ebias;
      #pragma unroll
      for (int p = 0; p < 32; ++p) a3 = dot2u(we[p], xs[tl * 32 + p], a3);
      zx[ob * 64 + tid] = (f16)a3;
    }
  }
}

// ---------------------------------------------------------------------------
// Recurrent kernel v10.1: v10 + PADDED h double-buffer.
// R19 post-mortem: SQ_LDS_BANK_CONFLICT jumped 0 -> 1.26e8 (~4 cyc per phase-B
// h-read). Cause: even lanes (k-half 0) read byte 16j, odd lanes byte 256+16j;
// 256 % 128 == 0 so both land on the SAME bank quad -> every dual-address
// b128 h-read serializes. Fix: hf[2][264] f16 — half 1 starts at f16 136
// (byte 272), so odd-lane quad base 17 ≡ quad+1 mod 8: even reads quad j%8,
// odd reads (j+1)%8, disjoint at every instruction. Writers: idx r + 8*(r>=128).
// ---------------------------------------------------------------------------
__global__ __launch_bounds__(512) void vrnn_rec(
    const f16* __restrict__ gix, const f16* __restrict__ zx,
    const float* __restrict__ eps,
    const uint32_t* __restrict__ whr, const uint32_t* __restrict__ whl_g,
    const uint32_t* __restrict__ whs, const uint32_t* __restrict__ whz,
    const uint32_t* __restrict__ wep_g,
    const float* __restrict__ b_hh,
    float* __restrict__ hws, float* __restrict__ out,
    int t0, int Tlen, int first, int last)
{
  const int t = threadIdx.x;
  const int b = blockIdx.x;
  const int r = t >> 1, q = t & 1;

  // ---- pinned register weights ----
  uint32_t wrg[3][REG_P];              // 36
  {
    const uint4* w4 = (const uint4*)whr;
    #pragma unroll
    for (int c = 0; c < 9; ++c) {
      uint4 v = w4[c * 512 + t];
      int rr = c / 3, p4 = c % 3;
      wrg[rr][4 * p4] = v.x; wrg[rr][4 * p4 + 1] = v.y;
      wrg[rr][4 * p4 + 2] = v.z; wrg[rr][4 * p4 + 3] = v.w;
    }
  }
  uint32_t wz[3][8];                   // 24
  {
    const uint4* w4 = (const uint4*)whz;
    #pragma unroll
    for (int c = 0; c < 6; ++c) {
      uint4 v = w4[c * 512 + t];
      int rr = c / 2, p4 = c % 2;
      wz[rr][4 * p4] = v.x; wz[rr][4 * p4 + 1] = v.y;
      wz[rr][4 * p4 + 2] = v.z; wz[rr][4 * p4 + 3] = v.w;
    }
  }
  uint32_t we[16];                     // 16
  {
    const uint4* w4 = (const uint4*)wep_g;
    #pragma unroll
    for (int c = 0; c < 4; ++c) {
      uint4 v = w4[c * 512 + t];
      we[4 * c] = v.x; we[4 * c + 1] = v.y; we[4 * c + 2] = v.z; we[4 * c + 3] = v.w;
    }
  }
  #pragma unroll
  for (int rr = 0; rr < 3; ++rr) {
    #pragma unroll
    for (int i = 0; i < REG_P; ++i) asm volatile("" : "+v"(wrg[rr][i]));
    #pragma unroll
    for (int i = 0; i < 8; ++i)    asm volatile("" : "+v"(wz[rr][i]));
  }
  #pragma unroll
  for (int i = 0; i < 16; ++i) asm volatile("" : "+v"(we[i]));
  const float bhn = b_hh[512 + r];

  // ---- LDS (~158.9 KB) ----
  __shared__ uint32_t lwh[512 * LDSTR];          // 155,648 B
  __shared__ __align__(16) f16 hf[2][264];       // padded: half1 at f16 136
  __shared__ float encp[512];
  __shared__ uint32_t zu[16];

  {
    const uint4* src = (const uint4*)(whl_g + (size_t)t * LDSTR);
    uint4* dst = (uint4*)(lwh + (size_t)t * LDSTR);
    #pragma unroll
    for (int j = 0; j < LDSTR / 4; ++j) dst[j] = src[j];
  }

  const int hwидx = r + ((r >> 7) << 3);   // padded write index for row r
  float hm = 0.0f;
  if (!q) {
    hm = first ? 0.0f : hws[b * 256 + r];
    hf[0][hwидx] = (f16)hm;
  }
  __syncthreads();   // once, outside the loop

  // ---- stream prefetch for t=0 ----
  float pf_g0 = 0.0f, pf_g1 = 0.0f, pf_g2 = 0.0f;
  if (!q) {
    const f16* gp0 = gix + (size_t)b * 768;
    pf_g0 = (float)gp0[r]; pf_g1 = (float)gp0[r + 256]; pf_g2 = (float)gp0[r + 512];
  }
  float pf_zm = 0.0f, pf_zl = 0.0f, pf_ep = 0.0f;
  if (t < 32) {
    const f16* zp = zx + (size_t)b * 64;
    pf_zm = (float)zp[t]; pf_zl = (float)zp[32 + t];
    pf_ep = eps[((size_t)t0 * NB + b) * 32 + t];
  }

  const int s = t >> 6;                       // wave id (phase-A k-slice)
  const int abase = 4 * s + (s >= 4 ? 1 : 0); // padded quad base of slice s (wave-uniform)
  const int bq = q ? 17 : 0;                  // padded quad base of this thread's k-half
  const uint32_t* myl = lwh + (size_t)t * LDSTR;
  const uint4* whs4 = (const uint4*)whs;

  // ---- preload stream chunk rr=0 for step 0 ----
  uint4 sbuf[7];
  #pragma unroll
  for (int j = 0; j < 7; ++j) sbuf[j] = whs4[j * 512 + t];
  __builtin_amdgcn_sched_barrier(0);

  for (int tl = 0; tl < Tlen; ++tl) {
    const int cur = tl & 1, nxt = cur ^ 1;
    const uint4* hu4 = (const uint4*)&hf[cur][0];

    // ---- phase A: encoder partials (wave-uniform h slice s) ----
    float ep_ = 0.0f;
    #pragma unroll
    for (int p4 = 0; p4 < 4; ++p4) {
      uint4 u4 = hu4[abase + p4];
      ep_ = dot2u(we[4 * p4],     u4.x, ep_);
      ep_ = dot2u(we[4 * p4 + 1], u4.y, ep_);
      ep_ = dot2u(we[4 * p4 + 2], u4.z, ep_);
      ep_ = dot2u(we[4 * p4 + 3], u4.w, ep_);
    }
    encp[t] = ep_;
    __syncthreads();  // b1

    // ---- phase B: z (32 threads) || gh (all threads, own k-half) ----
    if (t < 32) {
      float mu = pf_zm, lv = pf_zl;
      #pragma unroll
      for (int ss = 0; ss < 8; ++ss) {
        mu += encp[ss * 64 + t];
        lv += encp[ss * 64 + 32 + t];
      }
      float z = mu + pf_ep * exp2f(0.72134752f * lv);   // mu + eps*exp(0.5*lv)
      ((f16*)zu)[t] = (f16)z;
    }
    float g0 = 0.0f, g1 = 0.0f, g2 = 0.0f;
    // half-pairs [0,12): register weights
    #pragma unroll
    for (int g4 = 0; g4 < 3; ++g4) {
      uint4 u4 = hu4[bq + g4];
      g0 = dot2u(wrg[0][4 * g4],     u4.x, g0);
      g1 = dot2u(wrg[1][4 * g4],     u4.x, g1);
      g2 = dot2u(wrg[2][4 * g4],     u4.x, g2);
      g0 = dot2u(wrg[0][4 * g4 + 1], u4.y, g0);
      g1 = dot2u(wrg[1][4 * g4 + 1], u4.y, g1);
      g2 = dot2u(wrg[2][4 * g4 + 1], u4.y, g2);
      g0 = dot2u(wrg[0][4 * g4 + 2], u4.z, g0);
      g1 = dot2u(wrg[1][4 * g4 + 2], u4.z, g1);
      g2 = dot2u(wrg[2][4 * g4 + 2], u4.z, g2);
      g0 = dot2u(wrg[0][4 * g4 + 3], u4.w, g0);
      g1 = dot2u(wrg[1][4 * g4 + 3], u4.w, g1);
      g2 = dot2u(wrg[2][4 * g4 + 3], u4.w, g2);
    }
    // consume stream rr0 (half-pairs [36,64)) -> g0; issue rr1
    {
      float a = 0.0f;
      #pragma unroll
      for (int j = 0; j < 7; ++j) {
        uint4 u4 = hu4[bq + 9 + j];
        a = dot2u(sbuf[j].x, u4.x, a);
        a = dot2u(sbuf[j].y, u4.y, a);
        a = dot2u(sbuf[j].z, u4.z, a);
        a = dot2u(sbuf[j].w, u4.w, a);
      }
      g0 += a;
    }
    #pragma unroll
    for (int j = 0; j < 7; ++j) sbuf[j] = whs4[(7 + j) * 512 + t];
    __builtin_amdgcn_sched_barrier(0);
    // half-pairs [12,36) first half: LDS groups 0..2
    #pragma unroll
    for (int g4 = 0; g4 < 3; ++g4) {
      uint4 u4 = hu4[bq + 3 + g4];
      uint4 w0 = *(const uint4*)(myl + 0 * LDS_P + 4 * g4);
      uint4 w1 = *(const uint4*)(myl + 1 * LDS_P + 4 * g4);
      uint4 w2 = *(const uint4*)(myl + 2 * LDS_P + 4 * g4);
      g0 = dot2u(w0.x, u4.x, g0); g1 = dot2u(w1.x, u4.x, g1); g2 = dot2u(w2.x, u4.x, g2);
      g0 = dot2u(w0.y, u4.y, g0); g1 = dot2u(w1.y, u4.y, g1); g2 = dot2u(w2.y, u4.y, g2);
      g0 = dot2u(w0.z, u4.z, g0); g1 = dot2u(w1.z, u4.z, g1); g2 = dot2u(w2.z, u4.z, g2);
      g0 = dot2u(w0.w, u4.w, g0); g1 = dot2u(w1.w, u4.w, g1); g2 = dot2u(w2.w, u4.w, g2);
    }
    // consume stream rr1 -> g1; issue rr2
    {
      float a = 0.0f;
      #pragma unroll
      for (int j = 0; j < 7; ++j) {
        uint4 u4 = hu4[bq + 9 + j];
        a = dot2u(sbuf[j].x, u4.x, a);
        a = dot2u(sbuf[j].y, u4.y, a);
        a = dot2u(sbuf[j].z, u4.z, a);
        a = dot2u(sbuf[j].w, u4.w, a);
      }
      g1 += a;
    }
    #pragma unroll
    for (int j = 0; j < 7; ++j) sbuf[j] = whs4[(14 + j) * 512 + t];
    __builtin_amdgcn_sched_barrier(0);
    // half-pairs [12,36) second half: LDS groups 3..5
    #pragma unroll
    for (int g4 = 3; g4 < 6; ++g4) {
      uint4 u4 = hu4[bq + 3 + g4];
      uint4 w0 = *(const uint4*)(myl + 0 * LDS_P + 4 * g4);
      uint4 w1 = *(const uint4*)(myl + 1 * LDS_P + 4 * g4);
      uint4 w2 = *(const uint4*)(myl + 2 * LDS_P + 4 * g4);
      g0 = dot2u(w0.x, u4.x, g0); g1 = dot2u(w1.x, u4.x, g1); g2 = dot2u(w2.x, u4.x, g2);
      g0 = dot2u(w0.y, u4.y, g0); g1 = dot2u(w1.y, u4.y, g1); g2 = dot2u(w2.y, u4.y, g2);
      g0 = dot2u(w0.z, u4.z, g0); g1 = dot2u(w1.z, u4.z, g1); g2 = dot2u(w2.z, u4.z, g2);
      g0 = dot2u(w0.w, u4.w, g0); g1 = dot2u(w1.w, u4.w, g1); g2 = dot2u(w2.w, u4.w, g2);
    }
    // consume stream rr2 -> g2
    {
      float a = 0.0f;
      #pragma unroll
      for (int j = 0; j < 7; ++j) {
        uint4 u4 = hu4[bq + 9 + j];
        a = dot2u(sbuf[j].x, u4.x, a);
        a = dot2u(sbuf[j].y, u4.y, a);
        a = dot2u(sbuf[j].z, u4.z, a);
        a = dot2u(sbuf[j].w, u4.w, a);
      }
      g2 += a;
    }
    __syncthreads();  // b2  (zu visible)

    // ---- phase C: gi_z (own 8 z-pairs), pair-reduce, gates (even lanes) ----
    float q0 = 0.0f, q1 = 0.0f, q2 = 0.0f;
    #pragma unroll
    for (int p = 0; p < 8; ++p) {
      uint32_t u = zu[q * 8 + p];    // broadcast reads (banks p vs 8+p: disjoint)
      q0 = dot2u(wz[0][p], u, q0);
      q1 = dot2u(wz[1][p], u, q1);
      q2 = dot2u(wz[2][p], u, q2);
    }
    g0 += __shfl_xor(g0, 1); g1 += __shfl_xor(g1, 1); g2 += __shfl_xor(g2, 1);
    q0 += __shfl_xor(q0, 1); q1 += __shfl_xor(q1, 1); q2 += __shfl_xor(q2, 1);
    if (!q) {
      float rg = sigm(pf_g0 + g0 + q0);
      float uu = sigm(pf_g1 + g1 + q1);
      float n  = tanh_f(pf_g2 + q2 + rg * (g2 + bhn));
      hm = (1.0f - uu) * n + uu * hm;
      hf[nxt][hwидx] = (f16)hm;
    }

    // ---- issue stream rr0 for NEXT step ----
    #pragma unroll
    for (int j = 0; j < 7; ++j) sbuf[j] = whs4[j * 512 + t];
    __builtin_amdgcn_sched_barrier(0);

    // ---- prefetch activation streams for tl+1 ----
    int tn = (tl + 1 < Tlen) ? tl + 1 : tl;
    if (!q) {
      const f16* gp = gix + ((size_t)tn * NB + b) * 768;
      pf_g0 = (float)gp[r]; pf_g1 = (float)gp[r + 256]; pf_g2 = (float)gp[r + 512];
    }
    if (t < 32) {
      const f16* zp = zx + ((size_t)tn * NB + b) * 64;
      pf_zm = (float)zp[t]; pf_zl = (float)zp[32 + t];
      pf_ep = eps[((size_t)(t0 + tn) * NB + b) * 32 + t];
    }
    __syncthreads();  // b3  (h_new visible)
  }

  if (!q) {
    if (last) out[b * 256 + r] = hm;
    else      hws[b * 256 + r] = hm;
  }
}

extern "C" void kernel_launch(void* const* d_in, const int* in_sizes, int n_in,
                              void* d_out, int out_size, void* d_ws, size_t ws_size,
                              hipStream_t stream) {
  const float* x    = (const float*)d_in[0];
  const float* eps  = (const float*)d_in[1];
  const float* emW  = (const float*)d_in[2];
  const float* emb  = (const float*)d_in[3];
  const float* esW  = (const float*)d_in[4];
  const float* esb  = (const float*)d_in[5];
  const float* W_ih = (const float*)d_in[10];
  const float* W_hh = (const float*)d_in[11];
  const float* b_ih = (const float*)d_in[12];
  const float* b_hh = (const float*)d_in[13];
  float* out = (float*)d_out;

  // workspace layout (16B-aligned regions)
  const size_t o_whr = 262144;                  // hws: 256 KB
  const size_t o_whl = o_whr + 73728;           // whr: 9*512*16
  const size_t o_whs = o_whl + 155648;          // whl: 76*512*4
  const size_t o_whz = o_whs + 172032;          // whs: 21*512*16
  const size_t o_wep = o_whz + 49152;           // whz: 6*512*16
  const size_t o_gix = o_wep + 32768;           // wep: 4*512*16  -> 745,472
  int Tc = TSEQ;
  while (Tc > 8 && o_gix + (size_t)Tc * NB * (768 + 64) * 2 > ws_size) Tc >>= 1;

  float*    hws   = (float*)d_ws;
  uint32_t* whr   = (uint32_t*)((char*)d_ws + o_whr);
  uint32_t* whl_g = (uint32_t*)((char*)d_ws + o_whl);
  uint32_t* whs   = (uint32_t*)((char*)d_ws + o_whs);
  uint32_t* whz   = (uint32_t*)((char*)d_ws + o_whz);
  uint32_t* wep   = (uint32_t*)((char*)d_ws + o_wep);
  f16*      gix   = (f16*)((char*)d_ws + o_gix);
  f16*      zx    = gix + (size_t)Tc * NB * 768;

  vrnn_pack<<<dim3(1), dim3(512), 0, stream>>>(W_hh, W_ih, emW, esW,
                                               whr, whl_g, whs, whz, wep);

  int nch = TSEQ / Tc;
  int TT  = Tc < 64 ? Tc : 64;
  int nTT = Tc / TT;

  for (int c = 0; c < nch; ++c) {
    vrnn_pre<<<dim3(NB * nTT), dim3(256), 0, stream>>>(
        x, W_ih, b_ih, b_hh, emW, emb, esW, esb, gix, zx, c * Tc, TT, nTT);
    vrnn_rec<<<dim3(NB), dim3(512), 0, stream>>>(
        gix, zx, eps, whr, whl_g, whs, whz, wep, b_hh, hws, out,
        c * Tc, Tc, c == 0 ? 1 : 0, c == nch - 1 ? 1 : 0);
  }
}

// Round 21
// 2533.569 us; speedup vs baseline: 1.6263x; 1.0354x over previous
//
#include <hip/hip_runtime.h>
#include <stdint.h>

#define NB 256      // batch
#define TSEQ 1024   // sequence length
#define TT_MAX 64

// v10.2: 512 threads, K split between lane pairs. Per HALF-row (64 pairs = 16 quads):
// quads 0..3 reg, 4..9 LDS, 10..15 streamed in 3 k-chunks of 2 quads x 3 rows.
#define REG_P 16    // pairs in registers (3*16 = 48 VGPRs)
#define LDS_P 24    // pairs in LDS (3*24 = 72 u32/thread)
#define LDSTR 76    // u32 stride of per-thread LDS slice (proven 0-conflict R20)

typedef _Float16 f16;
typedef _Float16 h2 __attribute__((ext_vector_type(2)));

static __device__ __forceinline__ uint32_t pkh2(float a, float b) {
  h2 v; v[0] = (f16)a; v[1] = (f16)b;
  return __builtin_bit_cast(uint32_t, v);
}

#if __has_builtin(__builtin_amdgcn_fdot2)
static __device__ __forceinline__ float dot2u(uint32_t w, uint32_t h, float c) {
  return __builtin_amdgcn_fdot2(__builtin_bit_cast(h2, w), __builtin_bit_cast(h2, h), c, false);
}
#else
static __device__ __forceinline__ float dot2u(uint32_t w, uint32_t h, float c) {
  h2 a = __builtin_bit_cast(h2, w), b = __builtin_bit_cast(h2, h);
  return c + (float)a[0] * (float)b[0] + (float)a[1] * (float)b[1];
}
#endif

#if __has_builtin(__builtin_amdgcn_rcpf)
#define RCPF(x) __builtin_amdgcn_rcpf(x)
#else
#define RCPF(x) (1.0f / (x))
#endif

static __device__ __forceinline__ float sigm(float x) {
  return RCPF(1.0f + exp2f(-1.44269504f * x));
}
static __device__ __forceinline__ float tanh_f(float x) {
  return 1.0f - 2.0f * RCPF(1.0f + exp2f(2.88539008f * x));
}

// ---------------------------------------------------------------------------
// One-time weight pack (f16), 512-thread consumer layout.
// Thread t: row r=t>>1, k-half q=t&1 (f16-pairs [64q, 64q+64) of each row).
//  whr : [(rr*4+cj)*512 + t] uint4, quads 0..3 (pairs [0,16))
//  whl : [t*LDSTR + rr*24 + p],     pairs [16,40)
//  whs : [(m*6 + rr*2 + k)*512 + t] uint4 — k-chunk m (quads 10+2m, 11+2m),
//        row rr, quad-in-chunk k. Single-pass consume: h read once per chunk.
//  whz : [(rr*2+cj)*512 + t] uint4, z-pairs [8q, 8q+8)
//  wep : [p4*512 + t] uint4 — enc row e=t&63, k-slice s=t>>6 (16 pairs)
// ---------------------------------------------------------------------------
__global__ __launch_bounds__(512) void vrnn_pack(
    const float* __restrict__ W_hh, const float* __restrict__ W_ih,
    const float* __restrict__ emW, const float* __restrict__ esW,
    uint32_t* __restrict__ whr, uint32_t* __restrict__ whl,
    uint32_t* __restrict__ whs, uint32_t* __restrict__ whz,
    uint32_t* __restrict__ wep)
{
  const int t = threadIdx.x;
  const int r = t >> 1, q = t & 1;
  for (int rr = 0; rr < 3; ++rr) {
    const float* R = W_hh + (size_t)(r + rr * 256) * 256 + q * 128;
    for (int cj = 0; cj < 4; ++cj)
      for (int i = 0; i < 4; ++i) {
        int p = cj * 4 + i;
        whr[(((size_t)rr * 4 + cj) * 512 + t) * 4 + i] = pkh2(R[2 * p], R[2 * p + 1]);
      }
    for (int p = 0; p < LDS_P; ++p)
      whl[(size_t)t * LDSTR + rr * LDS_P + p] = pkh2(R[2 * (p + REG_P)], R[2 * (p + REG_P) + 1]);
    for (int m = 0; m < 3; ++m)
      for (int k = 0; k < 2; ++k)
        for (int i = 0; i < 4; ++i) {
          int p = (10 + 2 * m + k) * 4 + i;   // pairs [40,64)
          whs[(((size_t)m * 6 + rr * 2 + k) * 512 + t) * 4 + i] = pkh2(R[2 * p], R[2 * p + 1]);
        }
    const float* Z = W_ih + (size_t)(r + rr * 256) * 96 + 64 + q * 16;
    for (int cj = 0; cj < 2; ++cj)
      for (int i = 0; i < 4; ++i) {
        int p = cj * 4 + i;
        whz[(((size_t)rr * 2 + cj) * 512 + t) * 4 + i] = pkh2(Z[2 * p], Z[2 * p + 1]);
      }
  }
  {
    const int e = t & 63, s = t >> 6;
    const float* esrc = (e < 32) ? (emW + (size_t)e * 320 + 64)
                                 : (esW + (size_t)(e - 32) * 320 + 64);
    for (int p4 = 0; p4 < 4; ++p4)
      for (int i = 0; i < 4; ++i) {
        int pc = s * 16 + p4 * 4 + i;
        wep[((size_t)p4 * 512 + t) * 4 + i] = pkh2(esrc[2 * pc], esrc[2 * pc + 1]);
      }
  }
}

// ---------------------------------------------------------------------------
// Precompute kernel (unchanged): gi_x'[t][b][768], zx'[t][b][64]
// ---------------------------------------------------------------------------
__global__ __launch_bounds__(256, 2) void vrnn_pre(
    const float* __restrict__ x, const float* __restrict__ W_ih,
    const float* __restrict__ b_ih, const float* __restrict__ b_hh,
    const float* __restrict__ emW, const float* __restrict__ emb,
    const float* __restrict__ esW, const float* __restrict__ esb,
    f16* __restrict__ gix, f16* __restrict__ zx,
    int chunk_t0, int TT, int nTT)
{
  const int tid = threadIdx.x;
  const int b  = blockIdx.x / nTT;
  const int tt = blockIdx.x % nTT;
  const int tloc0 = tt * TT;

  uint32_t wx[3][32];
  float bias[3];
  #pragma unroll
  for (int rr = 0; rr < 3; ++rr) {
    int j = tid + rr * 256;
    const float4* wr = (const float4*)(W_ih + (size_t)j * 96);
    #pragma unroll
    for (int p4 = 0; p4 < 16; ++p4) {
      float4 v = wr[p4];
      wx[rr][2 * p4]     = pkh2(v.x, v.y);
      wx[rr][2 * p4 + 1] = pkh2(v.z, v.w);
    }
    bias[rr] = b_ih[j] + (rr < 2 ? b_hh[j] : 0.0f);  // fold b_hh into r,z rows only
  }
  uint32_t we[32]; float ebias = 0.0f;
  if (tid < 64) {
    const float* src = (tid < 32) ? (emW + (size_t)tid * 320)
                                  : (esW + (size_t)(tid - 32) * 320);
    #pragma unroll
    for (int p = 0; p < 32; ++p) we[p] = pkh2(src[2 * p], src[2 * p + 1]);
    ebias = (tid < 32) ? emb[tid] : esb[tid - 32];
  }

  __shared__ uint32_t xs[TT_MAX * 32];
  for (int idx = tid; idx < TT * 32; idx += 256) {
    int tl = idx >> 5, pk = idx & 31;
    size_t base = ((size_t)b * TSEQ + (chunk_t0 + tloc0 + tl)) * 64 + 2 * pk;
    xs[idx] = pkh2(x[base], x[base + 1]);
  }
  __syncthreads();

  for (int tl = 0; tl < TT; ++tl) {
    float a0 = bias[0], a1 = bias[1], a2 = bias[2];
    #pragma unroll
    for (int p = 0; p < 32; ++p) {
      uint32_t u = xs[tl * 32 + p];
      a0 = dot2u(wx[0][p], u, a0);
      a1 = dot2u(wx[1][p], u, a1);
      a2 = dot2u(wx[2][p], u, a2);
    }
    size_t ob = (size_t)(tloc0 + tl) * NB + b;
    f16* g = gix + ob * 768;
    g[tid] = (f16)a0; g[tid + 256] = (f16)a1; g[tid + 512] = (f16)a2;
    if (tid < 64) {
      float a3 = ebias;
      #pragma unroll
      for (int p = 0; p < 32; ++p) a3 = dot2u(we[p], xs[tl * 32 + p], a3);
      zx[ob * 64 + tid] = (f16)a3;
    }
  }
}

// ---------------------------------------------------------------------------
// Recurrent kernel v10.2: v10.1 + k-chunked stream (single-pass h reads).
// R20 post-mortem: conflicts 0, rec 1.18ms, VALUBusy 47%; top remaining LDS
// consumer = stream h re-reads (the 3 per-row passes re-read the SAME 7
// h-quads: 21 reads where 7 suffice). Re-partition stream along K: chunk m
// holds quads {10+2m, 11+2m} for ALL 3 rows (sbuf 6 uint4); consume reads 2
// h-quads once, dots 3 rows. LDS reads/thread/step 52 -> 38 (-27%).
// ---------------------------------------------------------------------------
__global__ __launch_bounds__(512) void vrnn_rec(
    const f16* __restrict__ gix, const f16* __restrict__ zx,
    const float* __restrict__ eps,
    const uint32_t* __restrict__ whr, const uint32_t* __restrict__ whl_g,
    const uint32_t* __restrict__ whs, const uint32_t* __restrict__ whz,
    const uint32_t* __restrict__ wep_g,
    const float* __restrict__ b_hh,
    float* __restrict__ hws, float* __restrict__ out,
    int t0, int Tlen, int first, int last)
{
  const int t = threadIdx.x;
  const int b = blockIdx.x;
  const int r = t >> 1, q = t & 1;

  // ---- pinned register weights ----
  uint32_t wrg[3][REG_P];              // 48
  {
    const uint4* w4 = (const uint4*)whr;
    #pragma unroll
    for (int c = 0; c < 12; ++c) {
      uint4 v = w4[c * 512 + t];
      int rr = c >> 2, p4 = c & 3;
      wrg[rr][4 * p4] = v.x; wrg[rr][4 * p4 + 1] = v.y;
      wrg[rr][4 * p4 + 2] = v.z; wrg[rr][4 * p4 + 3] = v.w;
    }
  }
  uint32_t wz[3][8];                   // 24
  {
    const uint4* w4 = (const uint4*)whz;
    #pragma unroll
    for (int c = 0; c < 6; ++c) {
      uint4 v = w4[c * 512 + t];
      int rr = c >> 1, p4 = c & 1;
      wz[rr][4 * p4] = v.x; wz[rr][4 * p4 + 1] = v.y;
      wz[rr][4 * p4 + 2] = v.z; wz[rr][4 * p4 + 3] = v.w;
    }
  }
  uint32_t we[16];                     // 16
  {
    const uint4* w4 = (const uint4*)wep_g;
    #pragma unroll
    for (int c = 0; c < 4; ++c) {
      uint4 v = w4[c * 512 + t];
      we[4 * c] = v.x; we[4 * c + 1] = v.y; we[4 * c + 2] = v.z; we[4 * c + 3] = v.w;
    }
  }
  #pragma unroll
  for (int rr = 0; rr < 3; ++rr) {
    #pragma unroll
    for (int i = 0; i < REG_P; ++i) asm volatile("" : "+v"(wrg[rr][i]));
    #pragma unroll
    for (int i = 0; i < 8; ++i)    asm volatile("" : "+v"(wz[rr][i]));
  }
  #pragma unroll
  for (int i = 0; i < 16; ++i) asm volatile("" : "+v"(we[i]));
  const float bhn = b_hh[512 + r];

  // ---- LDS (~158.9 KB) ----
  __shared__ uint32_t lwh[512 * LDSTR];          // 155,648 B
  __shared__ __align__(16) f16 hf[2][264];       // padded: half1 at f16 136 (R20 fix)
  __shared__ float encp[512];
  __shared__ uint32_t zu[16];

  {
    const uint4* src = (const uint4*)(whl_g + (size_t)t * LDSTR);
    uint4* dst = (uint4*)(lwh + (size_t)t * LDSTR);
    #pragma unroll
    for (int j = 0; j < LDSTR / 4; ++j) dst[j] = src[j];
  }

  const int hwidx = r + ((r >> 7) << 3);   // padded write index for row r
  float hm = 0.0f;
  if (!q) {
    hm = first ? 0.0f : hws[b * 256 + r];
    hf[0][hwidx] = (f16)hm;
  }
  __syncthreads();   // once, outside the loop

  // ---- stream prefetch for t=0 ----
  float pf_g0 = 0.0f, pf_g1 = 0.0f, pf_g2 = 0.0f;
  if (!q) {
    const f16* gp0 = gix + (size_t)b * 768;
    pf_g0 = (float)gp0[r]; pf_g1 = (float)gp0[r + 256]; pf_g2 = (float)gp0[r + 512];
  }
  float pf_zm = 0.0f, pf_zl = 0.0f, pf_ep = 0.0f;
  if (t < 32) {
    const f16* zp = zx + (size_t)b * 64;
    pf_zm = (float)zp[t]; pf_zl = (float)zp[32 + t];
    pf_ep = eps[((size_t)t0 * NB + b) * 32 + t];
  }

  const int s = t >> 6;                       // wave id (phase-A k-slice)
  const int abase = 4 * s + (s >= 4 ? 1 : 0); // padded quad base of slice s
  const int bq = q ? 17 : 0;                  // padded quad base of this k-half
  const uint32_t* myl = lwh + (size_t)t * LDSTR;
  const uint4* whs4 = (const uint4*)whs;

  // ---- preload stream k-chunk 0 for step 0 ----
  uint4 sbuf[6];
  #pragma unroll
  for (int j = 0; j < 6; ++j) sbuf[j] = whs4[j * 512 + t];
  __builtin_amdgcn_sched_barrier(0);

  for (int tl = 0; tl < Tlen; ++tl) {
    const int cur = tl & 1, nxt = cur ^ 1;
    const uint4* hu4 = (const uint4*)&hf[cur][0];

    // ---- phase A: encoder partials (wave-uniform h slice s) ----
    float ep_ = 0.0f;
    #pragma unroll
    for (int p4 = 0; p4 < 4; ++p4) {
      uint4 u4 = hu4[abase + p4];
      ep_ = dot2u(we[4 * p4],     u4.x, ep_);
      ep_ = dot2u(we[4 * p4 + 1], u4.y, ep_);
      ep_ = dot2u(we[4 * p4 + 2], u4.z, ep_);
      ep_ = dot2u(we[4 * p4 + 3], u4.w, ep_);
    }
    encp[t] = ep_;
    __syncthreads();  // b1

    // ---- phase B: z (32 threads) || gh (all threads, own k-half) ----
    if (t < 32) {
      float mu = pf_zm, lv = pf_zl;
      #pragma unroll
      for (int ss = 0; ss < 8; ++ss) {
        mu += encp[ss * 64 + t];
        lv += encp[ss * 64 + 32 + t];
      }
      float z = mu + pf_ep * exp2f(0.72134752f * lv);   // mu + eps*exp(0.5*lv)
      ((f16*)zu)[t] = (f16)z;
    }
    float g0 = 0.0f, g1 = 0.0f, g2 = 0.0f;
    // quads 0..3: register weights
    #pragma unroll
    for (int g4 = 0; g4 < 4; ++g4) {
      uint4 u4 = hu4[bq + g4];
      g0 = dot2u(wrg[0][4 * g4],     u4.x, g0);
      g1 = dot2u(wrg[1][4 * g4],     u4.x, g1);
      g2 = dot2u(wrg[2][4 * g4],     u4.x, g2);
      g0 = dot2u(wrg[0][4 * g4 + 1], u4.y, g0);
      g1 = dot2u(wrg[1][4 * g4 + 1], u4.y, g1);
      g2 = dot2u(wrg[2][4 * g4 + 1], u4.y, g2);
      g0 = dot2u(wrg[0][4 * g4 + 2], u4.z, g0);
      g1 = dot2u(wrg[1][4 * g4 + 2], u4.z, g1);
      g2 = dot2u(wrg[2][4 * g4 + 2], u4.z, g2);
      g0 = dot2u(wrg[0][4 * g4 + 3], u4.w, g0);
      g1 = dot2u(wrg[1][4 * g4 + 3], u4.w, g1);
      g2 = dot2u(wrg[2][4 * g4 + 3], u4.w, g2);
    }
    // consume stream chunk 0 (h quads 10,11 read ONCE); issue chunk 1
    {
      uint4 hq0 = hu4[bq + 10], hq1 = hu4[bq + 11];
      g0 = dot2u(sbuf[0].x, hq0.x, g0); g0 = dot2u(sbuf[0].y, hq0.y, g0);
      g0 = dot2u(sbuf[0].z, hq0.z, g0); g0 = dot2u(sbuf[0].w, hq0.w, g0);
      g1 = dot2u(sbuf[2].x, hq0.x, g1); g1 = dot2u(sbuf[2].y, hq0.y, g1);
      g1 = dot2u(sbuf[2].z, hq0.z, g1); g1 = dot2u(sbuf[2].w, hq0.w, g1);
      g2 = dot2u(sbuf[4].x, hq0.x, g2); g2 = dot2u(sbuf[4].y, hq0.y, g2);
      g2 = dot2u(sbuf[4].z, hq0.z, g2); g2 = dot2u(sbuf[4].w, hq0.w, g2);
      g0 = dot2u(sbuf[1].x, hq1.x, g0); g0 = dot2u(sbuf[1].y, hq1.y, g0);
      g0 = dot2u(sbuf[1].z, hq1.z, g0); g0 = dot2u(sbuf[1].w, hq1.w, g0);
      g1 = dot2u(sbuf[3].x, hq1.x, g1); g1 = dot2u(sbuf[3].y, hq1.y, g1);
      g1 = dot2u(sbuf[3].z, hq1.z, g1); g1 = dot2u(sbuf[3].w, hq1.w, g1);
      g2 = dot2u(sbuf[5].x, hq1.x, g2); g2 = dot2u(sbuf[5].y, hq1.y, g2);
      g2 = dot2u(sbuf[5].z, hq1.z, g2); g2 = dot2u(sbuf[5].w, hq1.w, g2);
    }
    #pragma unroll
    for (int j = 0; j < 6; ++j) sbuf[j] = whs4[(6 + j) * 512 + t];
    __builtin_amdgcn_sched_barrier(0);
    // LDS groups 0..2 (h quads 4..6)
    #pragma unroll
    for (int g4 = 0; g4 < 3; ++g4) {
      uint4 u4 = hu4[bq + 4 + g4];
      uint4 w0 = *(const uint4*)(myl + 0 * LDS_P + 4 * g4);
      uint4 w1 = *(const uint4*)(myl + 1 * LDS_P + 4 * g4);
      uint4 w2 = *(const uint4*)(myl + 2 * LDS_P + 4 * g4);
      g0 = dot2u(w0.x, u4.x, g0); g1 = dot2u(w1.x, u4.x, g1); g2 = dot2u(w2.x, u4.x, g2);
      g0 = dot2u(w0.y, u4.y, g0); g1 = dot2u(w1.y, u4.y, g1); g2 = dot2u(w2.y, u4.y, g2);
      g0 = dot2u(w0.z, u4.z, g0); g1 = dot2u(w1.z, u4.z, g1); g2 = dot2u(w2.z, u4.z, g2);
      g0 = dot2u(w0.w, u4.w, g0); g1 = dot2u(w1.w, u4.w, g1); g2 = dot2u(w2.w, u4.w, g2);
    }
    // consume stream chunk 1 (h quads 12,13); issue chunk 2
    {
      uint4 hq0 = hu4[bq + 12], hq1 = hu4[bq + 13];
      g0 = dot2u(sbuf[0].x, hq0.x, g0); g0 = dot2u(sbuf[0].y, hq0.y, g0);
      g0 = dot2u(sbuf[0].z, hq0.z, g0); g0 = dot2u(sbuf[0].w, hq0.w, g0);
      g1 = dot2u(sbuf[2].x, hq0.x, g1); g1 = dot2u(sbuf[2].y, hq0.y, g1);
      g1 = dot2u(sbuf[2].z, hq0.z, g1); g1 = dot2u(sbuf[2].w, hq0.w, g1);
      g2 = dot2u(sbuf[4].x, hq0.x, g2); g2 = dot2u(sbuf[4].y, hq0.y, g2);
      g2 = dot2u(sbuf[4].z, hq0.z, g2); g2 = dot2u(sbuf[4].w, hq0.w, g2);
      g0 = dot2u(sbuf[1].x, hq1.x, g0); g0 = dot2u(sbuf[1].y, hq1.y, g0);
      g0 = dot2u(sbuf[1].z, hq1.z, g0); g0 = dot2u(sbuf[1].w, hq1.w, g0);
      g1 = dot2u(sbuf[3].x, hq1.x, g1); g1 = dot2u(sbuf[3].y, hq1.y, g1);
      g1 = dot2u(sbuf[3].z, hq1.z, g1); g1 = dot2u(sbuf[3].w, hq1.w, g1);
      g2 = dot2u(sbuf[5].x, hq1.x, g2); g2 = dot2u(sbuf[5].y, hq1.y, g2);
      g2 = dot2u(sbuf[5].z, hq1.z, g2); g2 = dot2u(sbuf[5].w, hq1.w, g2);
    }
    #pragma unroll
    for (int j = 0; j < 6; ++j) sbuf[j] = whs4[(12 + j) * 512 + t];
    __builtin_amdgcn_sched_barrier(0);
    // LDS groups 3..5 (h quads 7..9)
    #pragma unroll
    for (int g4 = 3; g4 < 6; ++g4) {
      uint4 u4 = hu4[bq + 4 + g4];
      uint4 w0 = *(const uint4*)(myl + 0 * LDS_P + 4 * g4);
      uint4 w1 = *(const uint4*)(myl + 1 * LDS_P + 4 * g4);
      uint4 w2 = *(const uint4*)(myl + 2 * LDS_P + 4 * g4);
      g0 = dot2u(w0.x, u4.x, g0); g1 = dot2u(w1.x, u4.x, g1); g2 = dot2u(w2.x, u4.x, g2);
      g0 = dot2u(w0.y, u4.y, g0); g1 = dot2u(w1.y, u4.y, g1); g2 = dot2u(w2.y, u4.y, g2);
      g0 = dot2u(w0.z, u4.z, g0); g1 = dot2u(w1.z, u4.z, g1); g2 = dot2u(w2.z, u4.z, g2);
      g0 = dot2u(w0.w, u4.w, g0); g1 = dot2u(w1.w, u4.w, g1); g2 = dot2u(w2.w, u4.w, g2);
    }
    // consume stream chunk 2 (h quads 14,15)
    {
      uint4 hq0 = hu4[bq + 14], hq1 = hu4[bq + 15];
      g0 = dot2u(sbuf[0].x, hq0.x, g0); g0 = dot2u(sbuf[0].y, hq0.y, g0);
      g0 = dot2u(sbuf[0].z, hq0.z, g0); g0 = dot2u(sbuf[0].w, hq0.w, g0);
      g1 = dot2u(sbuf[2].x, hq0.x, g1); g1 = dot2u(sbuf[2].y, hq0.y, g1);
      g1 = dot2u(sbuf[2].z, hq0.z, g1); g1 = dot2u(sbuf[2].w, hq0.w, g1);
      g2 = dot2u(sbuf[4].x, hq0.x, g2); g2 = dot2u(sbuf[4].y, hq0.y, g2);
      g2 = dot2u(sbuf[4].z, hq0.z, g2); g2 = dot2u(sbuf[4].w, hq0.w, g2);
      g0 = dot2u(sbuf[1].x, hq1.x, g0); g0 = dot2u(sbuf[1].y, hq1.y, g0);
      g0 = dot2u(sbuf[1].z, hq1.z, g0); g0 = dot2u(sbuf[1].w, hq1.w, g0);
      g1 = dot2u(sbuf[3].x, hq1.x, g1); g1 = dot2u(sbuf[3].y, hq1.y, g1);
      g1 = dot2u(sbuf[3].z, hq1.z, g1); g1 = dot2u(sbuf[3].w, hq1.w, g1);
      g2 = dot2u(sbuf[5].x, hq1.x, g2); g2 = dot2u(sbuf[5].y, hq1.y, g2);
      g2 = dot2u(sbuf[5].z, hq1.z, g2); g2 = dot2u(sbuf[5].w, hq1.w, g2);
    }
    __syncthreads();  // b2  (zu visible)

    // ---- phase C: gi_z (own 8 z-pairs), pair-reduce, gates (even lanes) ----
    float q0 = 0.0f, q1 = 0.0f, q2 = 0.0f;
    #pragma unroll
    for (int p = 0; p < 8; ++p) {
      uint32_t u = zu[q * 8 + p];    // broadcast reads
      q0 = dot2u(wz[0][p], u, q0);
      q1 = dot2u(wz[1][p], u, q1);
      q2 = dot2u(wz[2][p], u, q2);
    }
    g0 += __shfl_xor(g0, 1); g1 += __shfl_xor(g1, 1); g2 += __shfl_xor(g2, 1);
    q0 += __shfl_xor(q0, 1); q1 += __shfl_xor(q1, 1); q2 += __shfl_xor(q2, 1);
    if (!q) {
      float rg = sigm(pf_g0 + g0 + q0);
      float uu = sigm(pf_g1 + g1 + q1);
      float n  = tanh_f(pf_g2 + q2 + rg * (g2 + bhn));
      hm = (1.0f - uu) * n + uu * hm;
      hf[nxt][hwidx] = (f16)hm;
    }

    // ---- issue stream chunk 0 for NEXT step ----
    #pragma unroll
    for (int j = 0; j < 6; ++j) sbuf[j] = whs4[j * 512 + t];
    __builtin_amdgcn_sched_barrier(0);

    // ---- prefetch activation streams for tl+1 ----
    int tn = (tl + 1 < Tlen) ? tl + 1 : tl;
    if (!q) {
      const f16* gp = gix + ((size_t)tn * NB + b) * 768;
      pf_g0 = (float)gp[r]; pf_g1 = (float)gp[r + 256]; pf_g2 = (float)gp[r + 512];
    }
    if (t < 32) {
      const f16* zp = zx + ((size_t)tn * NB + b) * 64;
      pf_zm = (float)zp[t]; pf_zl = (float)zp[32 + t];
      pf_ep = eps[((size_t)(t0 + tn) * NB + b) * 32 + t];
    }
    __syncthreads();  // b3  (h_new visible)
  }

  if (!q) {
    if (last) out[b * 256 + r] = hm;
    else      hws[b * 256 + r] = hm;
  }
}

extern "C" void kernel_launch(void* const* d_in, const int* in_sizes, int n_in,
                              void* d_out, int out_size, void* d_ws, size_t ws_size,
                              hipStream_t stream) {
  const float* x    = (const float*)d_in[0];
  const float* eps  = (const float*)d_in[1];
  const float* emW  = (const float*)d_in[2];
  const float* emb  = (const float*)d_in[3];
  const float* esW  = (const float*)d_in[4];
  const float* esb  = (const float*)d_in[5];
  const float* W_ih = (const float*)d_in[10];
  const float* W_hh = (const float*)d_in[11];
  const float* b_ih = (const float*)d_in[12];
  const float* b_hh = (const float*)d_in[13];
  float* out = (float*)d_out;

  // workspace layout (16B-aligned regions)
  const size_t o_whr = 262144;                  // hws: 256 KB
  const size_t o_whl = o_whr + 98304;           // whr: 12*512*16
  const size_t o_whs = o_whl + 155648;          // whl: 76*512*4
  const size_t o_whz = o_whs + 147456;          // whs: 18*512*16
  const size_t o_wep = o_whz + 49152;           // whz: 6*512*16
  const size_t o_gix = o_wep + 32768;           // wep: 4*512*16  -> 745,472
  int Tc = TSEQ;
  while (Tc > 8 && o_gix + (size_t)Tc * NB * (768 + 64) * 2 > ws_size) Tc >>= 1;

  float*    hws   = (float*)d_ws;
  uint32_t* whr   = (uint32_t*)((char*)d_ws + o_whr);
  uint32_t* whl_g = (uint32_t*)((char*)d_ws + o_whl);
  uint32_t* whs   = (uint32_t*)((char*)d_ws + o_whs);
  uint32_t* whz   = (uint32_t*)((char*)d_ws + o_whz);
  uint32_t* wep   = (uint32_t*)((char*)d_ws + o_wep);
  f16*      gix   = (f16*)((char*)d_ws + o_gix);
  f16*      zx    = gix + (size_t)Tc * NB * 768;

  vrnn_pack<<<dim3(1), dim3(512), 0, stream>>>(W_hh, W_ih, emW, esW,
                                               whr, whl_g, whs, whz, wep);

  int nch = TSEQ / Tc;
  int TT  = Tc < 64 ? Tc : 64;
  int nTT = Tc / TT;

  for (int c = 0; c < nch; ++c) {
    vrnn_pre<<<dim3(NB * nTT), dim3(256), 0, stream>>>(
        x, W_ih, b_ih, b_hh, emW, emb, esW, esb, gix, zx, c * Tc, TT, nTT);
    vrnn_rec<<<dim3(NB), dim3(512), 0, stream>>>(
        gix, zx, eps, whr, whl_g, whs, whz, wep, b_hh, hws, out,
        c * Tc, Tc, c == 0 ? 1 : 0, c == nch - 1 ? 1 : 0);
  }
}